// Round 8
// baseline (104.035 us; speedup 1.0000x reference)
//
#include <hip/hip_runtime.h>
#include <math.h>

// Problem constants
constexpr int D      = 512;
constexpr int NH     = 8;
constexpr int HD     = 64;
constexpr int WIN    = 128;
constexpr int DFF    = 2048;
constexpr int SEQ    = 4096;
constexpr float LN_EPS = 1e-5f;

typedef float f32x4 __attribute__((ext_vector_type(4)));
typedef __bf16 bf16x8 __attribute__((ext_vector_type(8)));

__device__ __forceinline__ unsigned short f2bf(float f) {
    union { float f; unsigned u; } v; v.f = f;
    unsigned r = v.u + 0x7FFF + ((v.u >> 16) & 1);   // round-to-nearest-even
    return (unsigned short)(r >> 16);
}
__device__ __forceinline__ float bf2f(unsigned short u) {
    union { unsigned u; float f; } v; v.u = (unsigned)u << 16; return v.f;
}

__device__ __forceinline__ void gload16(const void* g, void* l) {
    __builtin_amdgcn_global_load_lds(
        (const __attribute__((address_space(1))) unsigned int*)g,
        (__attribute__((address_space(3))) unsigned int*)l,
        16, 0, 0);
}

// ---------------------------------------------------------------------------
// prep: block [0,1024)  : x fp32 -> xb bf16 (2048 elems/block)
//       block [1024,4096): weight transposes W[K][N] fp32 -> Wt[N][K] bf16
// ---------------------------------------------------------------------------
__global__ __launch_bounds__(256) void prep(
    const float* __restrict__ x, unsigned short* __restrict__ xb,
    const float* __restrict__ qkv_w, const float* __restrict__ out_w,
    const float* __restrict__ w1,    const float* __restrict__ w2,
    unsigned short* __restrict__ qkvw_t, unsigned short* __restrict__ outw_t,
    unsigned short* __restrict__ w1_t,   unsigned short* __restrict__ w2_t)
{
    const int b = blockIdx.x;
    if (b < 1024) {
        int i = b * 2048 + threadIdx.x * 8;
        float4 v0 = *(const float4*)(x + i);
        float4 v1 = *(const float4*)(x + i + 4);
        ushort4 u0 = make_ushort4(f2bf(v0.x), f2bf(v0.y), f2bf(v0.z), f2bf(v0.w));
        ushort4 u1 = make_ushort4(f2bf(v1.x), f2bf(v1.y), f2bf(v1.z), f2bf(v1.w));
        *(ushort4*)(xb + i) = u0;
        *(ushort4*)(xb + i + 4) = u1;
        return;
    }
    __shared__ float t[32][33];
    const int b2 = b - 1024;
    const float* W; unsigned short* Wt; int K, N, nt, kt;
    if (b2 < 768)       { W = qkv_w; Wt = qkvw_t; K = 512;  N = 1536; nt = b2 % 48;          kt = b2 / 48; }
    else if (b2 < 1024) { W = out_w; Wt = outw_t; K = 512;  N = 512;  nt = (b2 - 768) % 16;  kt = (b2 - 768) / 16; }
    else if (b2 < 2048) { W = w1;    Wt = w1_t;   K = 512;  N = 2048; nt = (b2 - 1024) % 64; kt = (b2 - 1024) / 64; }
    else                { W = w2;    Wt = w2_t;   K = 2048; N = 512;  nt = (b2 - 2048) % 16; kt = (b2 - 2048) / 16; }
    const int tx = threadIdx.x & 31, ty = threadIdx.x >> 5;
    const int n0 = nt * 32, k0 = kt * 32;
    #pragma unroll
    for (int r = 0; r < 4; ++r)
        t[ty + r * 8][tx] = W[(size_t)(k0 + ty + r * 8) * N + n0 + tx];
    __syncthreads();
    #pragma unroll
    for (int r = 0; r < 4; ++r)
        Wt[(size_t)(n0 + ty + r * 8) * K + k0 + tx] = f2bf(t[tx][ty + r * 8]);
}

// ---------------------------------------------------------------------------
// Stage one BK=32 tile (A 128 rows + B 128 rows, 32 k = 64B each) into one
// 16KB buffer: A at [0,8K) row*64B, B at [8K,16K). 4 gloads/thread.
// ---------------------------------------------------------------------------
__device__ __forceinline__ void stage32(
    const unsigned short* __restrict__ A, const unsigned short* __restrict__ Bt,
    int K, int m0, int n0, int k0, char* buf, int tid)
{
    const int srow = (tid * 16) >> 6;   // 0..63
    const int skb  = (tid * 16) & 63;
    #pragma unroll
    for (int r = 0; r < 2; ++r) {
        const int row = srow + r * 64;
        gload16((const char*)A  + ((size_t)(m0 + row) * K + k0) * 2 + skb,
                buf +        r * 4096 + tid * 16);
        gload16((const char*)Bt + ((size_t)(n0 + row) * K + k0) * 2 + skb,
                buf + 8192 + r * 4096 + tid * 16);
    }
}

// ---------------------------------------------------------------------------
// GEMM core: 4-deep circular LDS pipeline, counted vmcnt (T3+T4).
// Per iter t:  s_waitcnt vmcnt(8)   (own tile-t loads retired; 2 stages fly)
//              s_barrier            (=> ALL waves' tile-t loads landed)
//              stage(t+3)           (overwrites buf[(t-1)&3], consumed by
//                                    all waves before barrier(t) -- safe)
//              ds_read frags(t); 16 MFMA.
// No vmcnt(0) in the loop. Tail stages go to a dummy region with clamped
// addresses so the vmcnt count stays exact. LDS: 4x16KB bufs + 16KB dummy.
// ---------------------------------------------------------------------------
__device__ __forceinline__ void gemm_core_pipe(
    const unsigned short* __restrict__ A, const unsigned short* __restrict__ Bt,
    int K, int m0, int n0, int kbeg, int kend, char* lds, f32x4 acc[4][4])
{
    const int tid  = threadIdx.x;
    const int lane = tid & 63;
    const int wave = tid >> 6;
    const int wr = wave >> 1, wc = wave & 1;
    const int lr = lane & 15, lk = lane >> 4;
    const int aoff = ((wr * 64 + lr) << 6) + (lk << 4);
    const int boff = 8192 + ((wc * 64 + lr) << 6) + (lk << 4);
    const int nt = (kend - kbeg) >> 5;
    char* dummy = lds + 65536;

    stage32(A, Bt, K, m0, n0, kbeg,      lds,         tid);
    stage32(A, Bt, K, m0, n0, kbeg + 32, lds + 16384, tid);
    stage32(A, Bt, K, m0, n0, kbeg + 64, lds + 32768, tid);

    for (int t = 0; t < nt; ++t) {
        asm volatile("s_waitcnt vmcnt(8)" ::: "memory");
        __builtin_amdgcn_s_barrier();
        __builtin_amdgcn_sched_barrier(0);

        // prefetch tile t+3 (dummy at tail keeps vmcnt arithmetic exact)
        {
            const bool real = (t + 3) < nt;
            const int  k3   = kbeg + (real ? (t + 3) : t) * 32;
            char* dst = real ? (lds + ((t + 3) & 3) * 16384) : dummy;
            stage32(A, Bt, K, m0, n0, k3, dst, tid);
        }

        const char* bufc = lds + (t & 3) * 16384;
        bf16x8 af[4], bfv[4];
        #pragma unroll
        for (int m = 0; m < 4; ++m)
            af[m] = *(const bf16x8*)(bufc + aoff + m * 1024);
        #pragma unroll
        for (int n = 0; n < 4; ++n)
            bfv[n] = *(const bf16x8*)(bufc + boff + n * 1024);

        #pragma unroll
        for (int m = 0; m < 4; ++m)
            #pragma unroll
            for (int n = 0; n < 4; ++n)
                acc[m][n] = __builtin_amdgcn_mfma_f32_16x16x32_bf16(
                    af[m], bfv[n], acc[m][n], 0, 0, 0);
        __builtin_amdgcn_sched_barrier(0);
    }
    asm volatile("s_waitcnt vmcnt(0)" ::: "memory");   // drain dummy DMAs
}

// ---------------------------------------------------------------------------
// Monolithic GEMM + bias (+ReLU), bf16 or fp32 out. 128x128 tile.
// ---------------------------------------------------------------------------
template <bool RELU, bool OUT_BF16>
__global__ __launch_bounds__(256) void gemm_mfma(
    const unsigned short* __restrict__ A,
    const unsigned short* __restrict__ Bt,
    const float* __restrict__ bias,
    void* __restrict__ Cv, int M, int N, int K)
{
    __shared__ __align__(16) char lds[81920];
    const int lane = threadIdx.x & 63;
    const int wave = threadIdx.x >> 6;
    const int wr = wave >> 1, wc = wave & 1;
    const int lr = lane & 15, lk = lane >> 4;
    const int m0 = blockIdx.y * 128, n0 = blockIdx.x * 128;

    f32x4 acc[4][4];
    #pragma unroll
    for (int m = 0; m < 4; ++m)
        #pragma unroll
        for (int n = 0; n < 4; ++n) acc[m][n] = f32x4{0.f, 0.f, 0.f, 0.f};

    gemm_core_pipe(A, Bt, K, m0, n0, 0, K, lds, acc);

    const int col0 = n0 + wc * 64 + lr;
    const int row0 = m0 + wr * 64 + lk * 4;
    #pragma unroll
    for (int m = 0; m < 4; ++m)
        #pragma unroll
        for (int n = 0; n < 4; ++n) {
            int col = col0 + n * 16;
            float bv = bias[col];
            #pragma unroll
            for (int j = 0; j < 4; ++j) {
                int row = row0 + m * 16 + j;
                float v = acc[m][n][j] + bv;
                if (RELU) v = fmaxf(v, 0.0f);
                if (OUT_BF16)
                    ((unsigned short*)Cv)[(size_t)row * N + col] = f2bf(v);
                else
                    ((float*)Cv)[(size_t)row * N + col] = v;
            }
        }
}

// ---------------------------------------------------------------------------
// Split-K GEMM: chunk z covers [z*Kc,(z+1)*Kc); writes bf16 partial to
// P + z*M*N (bias folded into chunk 0). Combined in the following add_ln.
// ---------------------------------------------------------------------------
__global__ __launch_bounds__(256) void gemm_splitk(
    const unsigned short* __restrict__ A,
    const unsigned short* __restrict__ Bt,
    const float* __restrict__ bias,
    unsigned short* __restrict__ P, int M, int N, int K, int Kc)
{
    __shared__ __align__(16) char lds[81920];
    const int lane = threadIdx.x & 63;
    const int wave = threadIdx.x >> 6;
    const int wr = wave >> 1, wc = wave & 1;
    const int lr = lane & 15, lk = lane >> 4;
    const int m0 = blockIdx.y * 128, n0 = blockIdx.x * 128;
    const int zc = blockIdx.z;

    f32x4 acc[4][4];
    #pragma unroll
    for (int m = 0; m < 4; ++m)
        #pragma unroll
        for (int n = 0; n < 4; ++n) acc[m][n] = f32x4{0.f, 0.f, 0.f, 0.f};

    gemm_core_pipe(A, Bt, K, m0, n0, zc * Kc, zc * Kc + Kc, lds, acc);

    unsigned short* Cp = P + (size_t)zc * M * N;
    const int col0 = n0 + wc * 64 + lr;
    const int row0 = m0 + wr * 64 + lk * 4;
    #pragma unroll
    for (int m = 0; m < 4; ++m)
        #pragma unroll
        for (int n = 0; n < 4; ++n) {
            int col = col0 + n * 16;
            float bv = (zc == 0) ? bias[col] : 0.0f;
            #pragma unroll
            for (int j = 0; j < 4; ++j) {
                int row = row0 + m * 16 + j;
                Cp[(size_t)row * N + col] = f2bf(acc[m][n][j] + bv);
            }
        }
}

// ---------------------------------------------------------------------------
// QKV GEMM: attention-layout epilogue. qb/kb [NH][SEQ][64], vtb [NH][64][SEQ].
// ---------------------------------------------------------------------------
__global__ __launch_bounds__(256) void gemm_qkv(
    const unsigned short* __restrict__ A,
    const unsigned short* __restrict__ Bt,
    const float* __restrict__ bias,
    unsigned short* __restrict__ qb,
    unsigned short* __restrict__ kb,
    unsigned short* __restrict__ vtb)
{
    constexpr int N = 3 * D, K = D;
    __shared__ __align__(16) char lds[81920];
    const int lane = threadIdx.x & 63;
    const int wave = threadIdx.x >> 6;
    const int wr = wave >> 1, wc = wave & 1;
    const int lr = lane & 15, lk = lane >> 4;
    const int m0 = blockIdx.y * 128, n0 = blockIdx.x * 128;

    f32x4 acc[4][4];
    #pragma unroll
    for (int m = 0; m < 4; ++m)
        #pragma unroll
        for (int n = 0; n < 4; ++n) acc[m][n] = f32x4{0.f, 0.f, 0.f, 0.f};

    gemm_core_pipe(A, Bt, K, m0, n0, 0, K, lds, acc);

    const int col0 = n0 + wc * 64 + lr;
    const int row0 = m0 + wr * 64 + lk * 4;
    const int region = n0 >> 9;   // 0=Q, 1=K, 2=V (uniform per block)
    #pragma unroll
    for (int m = 0; m < 4; ++m)
        #pragma unroll
        for (int n = 0; n < 4; ++n) {
            const int col = col0 + n * 16;
            const float bv = bias[col];
            const int rowm = row0 + m * 16;
            if (region == 2) {
                const int cc = col - 1024, hh = cc >> 6, dd = cc & 63;
                ushort4 u = make_ushort4(f2bf(acc[m][n][0] + bv),
                                         f2bf(acc[m][n][1] + bv),
                                         f2bf(acc[m][n][2] + bv),
                                         f2bf(acc[m][n][3] + bv));
                *(ushort4*)&vtb[((size_t)(hh * 64 + dd)) * SEQ + rowm] = u;
            } else {
                const int cc = col - region * 512, hh = cc >> 6, dd = cc & 63;
                unsigned short* dst = (region == 0) ? qb : kb;
                #pragma unroll
                for (int j = 0; j < 4; ++j)
                    dst[((size_t)hh * SEQ + rowm + j) * 64 + dd] =
                        f2bf(acc[m][n][j] + bv);
            }
        }
}

// ---------------------------------------------------------------------------
// MFMA windowed attention (unchanged).
// ---------------------------------------------------------------------------
__global__ __launch_bounds__(256) void attn_mfma(
    const unsigned short* __restrict__ qb,
    const unsigned short* __restrict__ kb,
    const unsigned short* __restrict__ vtb,
    unsigned short* __restrict__ o)
{
    constexpr float SCALE_L2E = 0.044194173824159216f * 1.4426950408889634f;
    __shared__ __align__(16) unsigned short P_lds[4][16][72];

    const int lane = threadIdx.x & 63;
    const int w    = threadIdx.x >> 6;
    const int i0   = blockIdx.x * 64;
    const int h    = blockIdx.y;
    const int lr = lane & 15, lg = lane >> 4;

    const unsigned short* qh = qb  + (size_t)h * SEQ * 64;
    const unsigned short* kh = kb  + (size_t)h * SEQ * 64;
    const unsigned short* vh = vtb + (size_t)h * 64 * SEQ;

    bf16x8 bq[2];
    {
        const unsigned short* qrow = qh + (size_t)(i0 + w * 16 + lr) * 64 + lg * 8;
        bq[0] = *(const bf16x8*)qrow;
        bq[1] = *(const bf16x8*)(qrow + 32);
    }

    f32x4 accO[4];
    #pragma unroll
    for (int n = 0; n < 4; ++n) accO[n] = f32x4{0.f, 0.f, 0.f, 0.f};
    float lsum = 0.0f;
    const int iq = i0 + w * 16 + lr;

    for (int c = 0; c < 5; ++c) {
        const int j0 = i0 - WIN + c * 64;
        if (j0 < 0 || j0 >= SEQ) continue;

        bf16x8 ak[2][4];
        #pragma unroll
        for (int m = 0; m < 4; ++m) {
            const unsigned short* kr = kh + (size_t)(j0 + m * 16 + lr) * 64 + lg * 8;
            ak[0][m] = *(const bf16x8*)kr;
            ak[1][m] = *(const bf16x8*)(kr + 32);
        }
        bf16x8 bv[2][4];
        #pragma unroll
        for (int n = 0; n < 4; ++n) {
            const unsigned short* vr = vh + (size_t)(n * 16 + lr) * SEQ + j0 + lg * 8;
            bv[0][n] = *(const bf16x8*)vr;
            bv[1][n] = *(const bf16x8*)(vr + 32);
        }

        f32x4 accS[4];
        #pragma unroll
        for (int m = 0; m < 4; ++m) {
            accS[m] = f32x4{0.f, 0.f, 0.f, 0.f};
            #pragma unroll
            for (int s = 0; s < 2; ++s)
                accS[m] = __builtin_amdgcn_mfma_f32_16x16x32_bf16(
                    ak[s][m], bq[s], accS[m], 0, 0, 0);
        }

        #pragma unroll
        for (int m = 0; m < 4; ++m) {
            const int kbase = j0 + m * 16 + lg * 4;
            float p0, p1, p2, p3;
            {
                int d0 = kbase + 0 - iq; bool v0 = (d0 >= -WIN) && (d0 <= WIN);
                int d1 = kbase + 1 - iq; bool v1 = (d1 >= -WIN) && (d1 <= WIN);
                int d2 = kbase + 2 - iq; bool v2 = (d2 >= -WIN) && (d2 <= WIN);
                int d3 = kbase + 3 - iq; bool v3 = (d3 >= -WIN) && (d3 <= WIN);
                p0 = v0 ? exp2f(accS[m][0] * SCALE_L2E) : 0.0f;
                p1 = v1 ? exp2f(accS[m][1] * SCALE_L2E) : 0.0f;
                p2 = v2 ? exp2f(accS[m][2] * SCALE_L2E) : 0.0f;
                p3 = v3 ? exp2f(accS[m][3] * SCALE_L2E) : 0.0f;
            }
            lsum += (p0 + p1) + (p2 + p3);
            ushort4 pk = make_ushort4(f2bf(p0), f2bf(p1), f2bf(p2), f2bf(p3));
            *(ushort4*)&P_lds[w][lr][m * 16 + lg * 4] = pk;
        }

        bf16x8 pa[2];
        pa[0] = *(const bf16x8*)&P_lds[w][lr][lg * 8];
        pa[1] = *(const bf16x8*)&P_lds[w][lr][32 + lg * 8];

        #pragma unroll
        for (int n = 0; n < 4; ++n)
            #pragma unroll
            for (int s = 0; s < 2; ++s)
                accO[n] = __builtin_amdgcn_mfma_f32_16x16x32_bf16(
                    pa[s], bv[s][n], accO[n], 0, 0, 0);
    }

    lsum += __shfl_xor(lsum, 16, 64);
    lsum += __shfl_xor(lsum, 32, 64);
    float rinv[4];
    #pragma unroll
    for (int j = 0; j < 4; ++j)
        rinv[j] = 1.0f / __shfl(lsum, lg * 4 + j, 64);

    #pragma unroll
    for (int n = 0; n < 4; ++n)
        #pragma unroll
        for (int j = 0; j < 4; ++j) {
            int row = i0 + w * 16 + lg * 4 + j;
            int col = h * 64 + n * 16 + lr;
            o[(size_t)row * D + col] = f2bf(accO[n][j] * rinv[j]);
        }
}

// ---------------------------------------------------------------------------
// out = LayerNorm(residual + sum_{p<NP} P_bf16[p]) * g + beta.
// ---------------------------------------------------------------------------
template <int NP, bool RES_BF16, bool OUT_BF16>
__global__ __launch_bounds__(256) void add_ln(
    const void* __restrict__ res, const unsigned short* __restrict__ P,
    size_t pstride,
    const float* __restrict__ g, const float* __restrict__ beta,
    void* __restrict__ out)
{
    const int wave = threadIdx.x >> 6;
    const int lane = threadIdx.x & 63;
    const int row = blockIdx.x * 4 + wave;
    const size_t rbase = (size_t)row * D;

    float v[8];
    float sum = 0.0f, sumsq = 0.0f;
    #pragma unroll
    for (int e = 0; e < 8; ++e) {
        int c = lane + e * 64;
        float z = RES_BF16 ? bf2f(((const unsigned short*)res)[rbase + c])
                           : ((const float*)res)[rbase + c];
        #pragma unroll
        for (int p = 0; p < NP; ++p)
            z += bf2f(P[p * pstride + rbase + c]);
        v[e] = z;
        sum += z;
        sumsq += z * z;
    }
    #pragma unroll
    for (int off = 32; off; off >>= 1) {
        sum   += __shfl_xor(sum, off, 64);
        sumsq += __shfl_xor(sumsq, off, 64);
    }
    const float mu   = sum * (1.0f / D);
    const float var  = sumsq * (1.0f / D) - mu * mu;
    const float rstd = rsqrtf(var + LN_EPS);

    #pragma unroll
    for (int e = 0; e < 8; ++e) {
        int c = lane + e * 64;
        float r = (v[e] - mu) * rstd * g[c] + beta[c];
        if (OUT_BF16) ((unsigned short*)out)[rbase + c] = f2bf(r);
        else          ((float*)out)[rbase + c] = r;
    }
}

// ---------------------------------------------------------------------------
extern "C" void kernel_launch(void* const* d_in, const int* in_sizes, int n_in,
                              void* d_out, int out_size, void* d_ws, size_t ws_size,
                              hipStream_t stream)
{
    const float* x      = (const float*)d_in[0];
    const float* qkv_w  = (const float*)d_in[1];
    const float* qkv_b  = (const float*)d_in[2];
    const float* out_w  = (const float*)d_in[3];
    const float* out_b  = (const float*)d_in[4];
    const float* ln1_g  = (const float*)d_in[5];
    const float* ln1_b  = (const float*)d_in[6];
    const float* w1     = (const float*)d_in[7];
    const float* b1     = (const float*)d_in[8];
    const float* w2     = (const float*)d_in[9];
    const float* b2     = (const float*)d_in[10];
    const float* ln2_g  = (const float*)d_in[11];
    const float* ln2_b  = (const float*)d_in[12];
    float* out = (float*)d_out;

    // ---- workspace layout (flat, no aliasing; 70 MiB total) ----
    constexpr size_t MiB = 1u << 20;
    char* base = (char*)d_ws;
    unsigned short* xb     = (unsigned short*)(base + 0);                     // 4
    unsigned short* qkvw_t = (unsigned short*)(base + 4 * MiB);               // 1.5
    unsigned short* outw_t = (unsigned short*)(base + 5 * MiB + 512 * 1024);  // 0.5
    unsigned short* w1_t   = (unsigned short*)(base + 6 * MiB);               // 2
    unsigned short* w2_t   = (unsigned short*)(base + 8 * MiB);               // 2
    unsigned short* qbuf   = (unsigned short*)(base + 10 * MiB);              // 4
    unsigned short* kbuf   = (unsigned short*)(base + 14 * MiB);              // 4
    unsigned short* vtbuf  = (unsigned short*)(base + 18 * MiB);              // 4
    unsigned short* o_b    = (unsigned short*)(base + 22 * MiB);              // 4
    unsigned short* pOut   = (unsigned short*)(base + 26 * MiB);              // 8  (2 partials)
    unsigned short* x1b    = (unsigned short*)(base + 34 * MiB);              // 4
    unsigned short* ff1b   = (unsigned short*)(base + 38 * MiB);              // 16
    unsigned short* pFF2   = (unsigned short*)(base + 54 * MiB);              // 16 (4 partials)

    // 0) conversions + weight transposes (one kernel)
    prep<<<4096, 256, 0, stream>>>(x, xb, qkv_w, out_w, w1, w2,
                                   qkvw_t, outw_t, w1_t, w2_t);

    // 1) qkv projection -> qb/kb/vtb (4-deep pipeline)
    gemm_qkv<<<dim3(3 * D / 128, SEQ / 128), 256, 0, stream>>>(
        xb, qkvw_t, qkv_b, qbuf, kbuf, vtbuf);

    // 2) MFMA windowed attention -> o bf16
    attn_mfma<<<dim3(SEQ / 64, NH), 256, 0, stream>>>(qbuf, kbuf, vtbuf, o_b);

    // 3) out-proj, split-K 2 -> bf16 partials
    gemm_splitk<<<dim3(D / 128, SEQ / 128, 2), 256, 0, stream>>>(
        o_b, outw_t, out_b, pOut, SEQ, D, D, D / 2);

    // 4) x1b = bf16( LN(x + p0 + p1) )
    add_ln<2, false, true><<<SEQ / 4, 256, 0, stream>>>(
        x, pOut, (size_t)SEQ * D, ln1_g, ln1_b, x1b);

    // 5) ff1 = relu(x1b @ w1 + b1) -> bf16
    gemm_mfma<true, true><<<dim3(DFF / 128, SEQ / 128), 256, 0, stream>>>(
        x1b, w1_t, b1, ff1b, SEQ, DFF, D);

    // 6) ff2 split-K 4 -> bf16 partials
    gemm_splitk<<<dim3(D / 128, SEQ / 128, 4), 256, 0, stream>>>(
        ff1b, w2_t, b2, pFF2, SEQ, D, DFF, DFF / 4);

    // 7) out = LN(x1b + p0+p1+p2+p3) -> fp32
    add_ln<4, true, false><<<SEQ / 4, 256, 0, stream>>>(
        x1b, pFF2, (size_t)SEQ * D, ln2_g, ln2_b, out);
}

// Round 9
// 95.607 us; speedup vs baseline: 1.0882x; 1.0882x over previous
//
#include <hip/hip_runtime.h>
#include <math.h>

// Problem constants
constexpr int D      = 512;
constexpr int NH     = 8;
constexpr int HD     = 64;
constexpr int WIN    = 128;
constexpr int DFF    = 2048;
constexpr int SEQ    = 4096;
constexpr float LN_EPS = 1e-5f;

typedef float f32x4 __attribute__((ext_vector_type(4)));
typedef __bf16 bf16x8 __attribute__((ext_vector_type(8)));

__device__ __forceinline__ unsigned short f2bf(float f) {
    union { float f; unsigned u; } v; v.f = f;
    unsigned r = v.u + 0x7FFF + ((v.u >> 16) & 1);   // round-to-nearest-even
    return (unsigned short)(r >> 16);
}
__device__ __forceinline__ float bf2f(unsigned short u) {
    union { unsigned u; float f; } v; v.u = (unsigned)u << 16; return v.f;
}

__device__ __forceinline__ void gload16(const void* g, void* l) {
    __builtin_amdgcn_global_load_lds(
        (const __attribute__((address_space(1))) unsigned int*)g,
        (__attribute__((address_space(3))) unsigned int*)l,
        16, 0, 0);
}

// ---------------------------------------------------------------------------
// prep: block [0,1024)  : x fp32 -> xb bf16 (2048 elems/block)
//       block [1024,4096): weight transposes W[K][N] fp32 -> Wt[N][K] bf16
// ---------------------------------------------------------------------------
__global__ __launch_bounds__(256) void prep(
    const float* __restrict__ x, unsigned short* __restrict__ xb,
    const float* __restrict__ qkv_w, const float* __restrict__ out_w,
    const float* __restrict__ w1,    const float* __restrict__ w2,
    unsigned short* __restrict__ qkvw_t, unsigned short* __restrict__ outw_t,
    unsigned short* __restrict__ w1_t,   unsigned short* __restrict__ w2_t)
{
    const int b = blockIdx.x;
    if (b < 1024) {
        int i = b * 2048 + threadIdx.x * 8;
        float4 v0 = *(const float4*)(x + i);
        float4 v1 = *(const float4*)(x + i + 4);
        ushort4 u0 = make_ushort4(f2bf(v0.x), f2bf(v0.y), f2bf(v0.z), f2bf(v0.w));
        ushort4 u1 = make_ushort4(f2bf(v1.x), f2bf(v1.y), f2bf(v1.z), f2bf(v1.w));
        *(ushort4*)(xb + i) = u0;
        *(ushort4*)(xb + i + 4) = u1;
        return;
    }
    __shared__ float t[32][33];
    const int b2 = b - 1024;
    const float* W; unsigned short* Wt; int K, N, nt, kt;
    if (b2 < 768)       { W = qkv_w; Wt = qkvw_t; K = 512;  N = 1536; nt = b2 % 48;          kt = b2 / 48; }
    else if (b2 < 1024) { W = out_w; Wt = outw_t; K = 512;  N = 512;  nt = (b2 - 768) % 16;  kt = (b2 - 768) / 16; }
    else if (b2 < 2048) { W = w1;    Wt = w1_t;   K = 512;  N = 2048; nt = (b2 - 1024) % 64; kt = (b2 - 1024) / 64; }
    else                { W = w2;    Wt = w2_t;   K = 2048; N = 512;  nt = (b2 - 2048) % 16; kt = (b2 - 2048) / 16; }
    const int tx = threadIdx.x & 31, ty = threadIdx.x >> 5;
    const int n0 = nt * 32, k0 = kt * 32;
    #pragma unroll
    for (int r = 0; r < 4; ++r)
        t[ty + r * 8][tx] = W[(size_t)(k0 + ty + r * 8) * N + n0 + tx];
    __syncthreads();
    #pragma unroll
    for (int r = 0; r < 4; ++r)
        Wt[(size_t)(n0 + ty + r * 8) * K + k0 + tx] = f2bf(t[tx][ty + r * 8]);
}

// ---------------------------------------------------------------------------
// Stage one BK=64 tile with 512 threads (1 gload16 per thread per quarter):
// LDS buf layout: Ah0 [0,8K) | Ah1 [8K,16K) | Bh0 [16K,24K) | Bh1 [24K,32K),
// each half = [128 rows][64B].
// ---------------------------------------------------------------------------
__device__ __forceinline__ void stage64_8w(
    const unsigned short* __restrict__ A, const unsigned short* __restrict__ Bt,
    int K, int m0, int n0, int k0, char* buf, int tid)
{
    const int row = tid >> 2;          // 0..127
    const int kb  = (tid & 3) * 16;    // byte within 64B half-row
    const char* pa = (const char*)A  + ((size_t)(m0 + row) * K + k0) * 2 + kb;
    const char* pb = (const char*)Bt + ((size_t)(n0 + row) * K + k0) * 2 + kb;
    char* dst = buf + tid * 16;        // == row*64 + kb
    gload16(pa,      dst);
    gload16(pa + 64, dst + 8192);
    gload16(pb,      dst + 16384);
    gload16(pb + 64, dst + 24576);
}

// ---------------------------------------------------------------------------
// GEMM core, 8 waves (512 thr), 128x128 tile, BK=64, 2-phase double buffer
// (round-7 structure, reverted from the round-8 counted-vmcnt pipeline which
// regressed). Wave wv = (wr=wv>>2, wc=wv&3) owns a 64x32 sub-tile:
// 4 m-frags x 2 n-frags of 16x16x32. 16 waves/CU when 2 blocks co-reside.
// ---------------------------------------------------------------------------
__device__ __forceinline__ void gemm_core_db8(
    const unsigned short* __restrict__ A, const unsigned short* __restrict__ Bt,
    int K, int m0, int n0, int kbeg, int kend, char* lds, f32x4 acc[4][2])
{
    const int tid  = threadIdx.x;
    const int lane = tid & 63;
    const int wave = tid >> 6;            // 0..7
    const int wr = wave >> 2, wc = wave & 3;
    const int lr = lane & 15, lk = lane >> 4;
    const int aoff = ((wr * 64 + lr) << 6) + (lk << 4);
    const int boff = 16384 + ((wc * 32 + lr) << 6) + (lk << 4);

    stage64_8w(A, Bt, K, m0, n0, kbeg, lds, tid);
    __syncthreads();

    int cur = 0;
    for (int k0 = kbeg; k0 < kend; k0 += 64) {
        char* bufc = lds + cur * 32768;
        if (k0 + 64 < kend)
            stage64_8w(A, Bt, K, m0, n0, k0 + 64, lds + (cur ^ 1) * 32768, tid);

        bf16x8 af[2][4], bfv[2][2];
        #pragma unroll
        for (int m = 0; m < 4; ++m) {
            af[0][m] = *(const bf16x8*)(bufc +        aoff + m * 1024);
            af[1][m] = *(const bf16x8*)(bufc + 8192 + aoff + m * 1024);
        }
        #pragma unroll
        for (int n = 0; n < 2; ++n) {
            bfv[0][n] = *(const bf16x8*)(bufc +        boff + n * 1024);
            bfv[1][n] = *(const bf16x8*)(bufc + 8192 + boff + n * 1024);
        }
        #pragma unroll
        for (int ks = 0; ks < 2; ++ks)
            #pragma unroll
            for (int m = 0; m < 4; ++m)
                #pragma unroll
                for (int n = 0; n < 2; ++n)
                    acc[m][n] = __builtin_amdgcn_mfma_f32_16x16x32_bf16(
                        af[ks][m], bfv[ks][n], acc[m][n], 0, 0, 0);

        __syncthreads();   // drains this iter's prefetch; buf swap safe
        cur ^= 1;
    }
}

// ---------------------------------------------------------------------------
// Monolithic GEMM + bias (+ReLU), bf16 or fp32 out. 128x128 tile, 8 waves.
// ---------------------------------------------------------------------------
template <bool RELU, bool OUT_BF16>
__global__ __launch_bounds__(512) void gemm_mfma(
    const unsigned short* __restrict__ A,
    const unsigned short* __restrict__ Bt,
    const float* __restrict__ bias,
    void* __restrict__ Cv, int M, int N, int K)
{
    __shared__ __align__(16) char lds[65536];
    const int lane = threadIdx.x & 63;
    const int wave = threadIdx.x >> 6;
    const int wr = wave >> 2, wc = wave & 3;
    const int lr = lane & 15, lk = lane >> 4;
    const int m0 = blockIdx.y * 128, n0 = blockIdx.x * 128;

    f32x4 acc[4][2];
    #pragma unroll
    for (int m = 0; m < 4; ++m)
        #pragma unroll
        for (int n = 0; n < 2; ++n) acc[m][n] = f32x4{0.f, 0.f, 0.f, 0.f};

    gemm_core_db8(A, Bt, K, m0, n0, 0, K, lds, acc);

    const int col0 = n0 + wc * 32 + lr;
    const int row0 = m0 + wr * 64 + lk * 4;
    #pragma unroll
    for (int m = 0; m < 4; ++m)
        #pragma unroll
        for (int n = 0; n < 2; ++n) {
            int col = col0 + n * 16;
            float bv = bias[col];
            #pragma unroll
            for (int j = 0; j < 4; ++j) {
                int row = row0 + m * 16 + j;
                float v = acc[m][n][j] + bv;
                if (RELU) v = fmaxf(v, 0.0f);
                if (OUT_BF16)
                    ((unsigned short*)Cv)[(size_t)row * N + col] = f2bf(v);
                else
                    ((float*)Cv)[(size_t)row * N + col] = v;
            }
        }
}

// ---------------------------------------------------------------------------
// Split-K GEMM: chunk z covers [z*Kc,(z+1)*Kc); writes bf16 partial to
// P + z*M*N (bias folded into chunk 0). Combined in the following add_ln.
// ---------------------------------------------------------------------------
__global__ __launch_bounds__(512) void gemm_splitk(
    const unsigned short* __restrict__ A,
    const unsigned short* __restrict__ Bt,
    const float* __restrict__ bias,
    unsigned short* __restrict__ P, int M, int N, int K, int Kc)
{
    __shared__ __align__(16) char lds[65536];
    const int lane = threadIdx.x & 63;
    const int wave = threadIdx.x >> 6;
    const int wr = wave >> 2, wc = wave & 3;
    const int lr = lane & 15, lk = lane >> 4;
    const int m0 = blockIdx.y * 128, n0 = blockIdx.x * 128;
    const int zc = blockIdx.z;

    f32x4 acc[4][2];
    #pragma unroll
    for (int m = 0; m < 4; ++m)
        #pragma unroll
        for (int n = 0; n < 2; ++n) acc[m][n] = f32x4{0.f, 0.f, 0.f, 0.f};

    gemm_core_db8(A, Bt, K, m0, n0, zc * Kc, zc * Kc + Kc, lds, acc);

    unsigned short* Cp = P + (size_t)zc * M * N;
    const int col0 = n0 + wc * 32 + lr;
    const int row0 = m0 + wr * 64 + lk * 4;
    #pragma unroll
    for (int m = 0; m < 4; ++m)
        #pragma unroll
        for (int n = 0; n < 2; ++n) {
            int col = col0 + n * 16;
            float bv = (zc == 0) ? bias[col] : 0.0f;
            #pragma unroll
            for (int j = 0; j < 4; ++j) {
                int row = row0 + m * 16 + j;
                Cp[(size_t)row * N + col] = f2bf(acc[m][n][j] + bv);
            }
        }
}

// ---------------------------------------------------------------------------
// QKV GEMM: attention-layout epilogue. qb/kb [NH][SEQ][64], vtb [NH][64][SEQ].
// ---------------------------------------------------------------------------
__global__ __launch_bounds__(512) void gemm_qkv(
    const unsigned short* __restrict__ A,
    const unsigned short* __restrict__ Bt,
    const float* __restrict__ bias,
    unsigned short* __restrict__ qb,
    unsigned short* __restrict__ kb,
    unsigned short* __restrict__ vtb)
{
    constexpr int N = 3 * D, K = D;
    __shared__ __align__(16) char lds[65536];
    const int lane = threadIdx.x & 63;
    const int wave = threadIdx.x >> 6;
    const int wr = wave >> 2, wc = wave & 3;
    const int lr = lane & 15, lk = lane >> 4;
    const int m0 = blockIdx.y * 128, n0 = blockIdx.x * 128;

    f32x4 acc[4][2];
    #pragma unroll
    for (int m = 0; m < 4; ++m)
        #pragma unroll
        for (int n = 0; n < 2; ++n) acc[m][n] = f32x4{0.f, 0.f, 0.f, 0.f};

    gemm_core_db8(A, Bt, K, m0, n0, 0, K, lds, acc);

    const int col0 = n0 + wc * 32 + lr;
    const int row0 = m0 + wr * 64 + lk * 4;
    const int region = n0 >> 9;   // 0=Q, 1=K, 2=V (uniform per block)
    #pragma unroll
    for (int m = 0; m < 4; ++m)
        #pragma unroll
        for (int n = 0; n < 2; ++n) {
            const int col = col0 + n * 16;
            const float bv = bias[col];
            const int rowm = row0 + m * 16;
            if (region == 2) {
                const int cc = col - 1024, hh = cc >> 6, dd = cc & 63;
                ushort4 u = make_ushort4(f2bf(acc[m][n][0] + bv),
                                         f2bf(acc[m][n][1] + bv),
                                         f2bf(acc[m][n][2] + bv),
                                         f2bf(acc[m][n][3] + bv));
                *(ushort4*)&vtb[((size_t)(hh * 64 + dd)) * SEQ + rowm] = u;
            } else {
                const int cc = col - region * 512, hh = cc >> 6, dd = cc & 63;
                unsigned short* dst = (region == 0) ? qb : kb;
                #pragma unroll
                for (int j = 0; j < 4; ++j)
                    dst[((size_t)hh * SEQ + rowm + j) * 64 + dd] =
                        f2bf(acc[m][n][j] + bv);
            }
        }
}

// ---------------------------------------------------------------------------
// MFMA windowed attention (unchanged).
// ---------------------------------------------------------------------------
__global__ __launch_bounds__(256) void attn_mfma(
    const unsigned short* __restrict__ qb,
    const unsigned short* __restrict__ kb,
    const unsigned short* __restrict__ vtb,
    unsigned short* __restrict__ o)
{
    constexpr float SCALE_L2E = 0.044194173824159216f * 1.4426950408889634f;
    __shared__ __align__(16) unsigned short P_lds[4][16][72];

    const int lane = threadIdx.x & 63;
    const int w    = threadIdx.x >> 6;
    const int i0   = blockIdx.x * 64;
    const int h    = blockIdx.y;
    const int lr = lane & 15, lg = lane >> 4;

    const unsigned short* qh = qb  + (size_t)h * SEQ * 64;
    const unsigned short* kh = kb  + (size_t)h * SEQ * 64;
    const unsigned short* vh = vtb + (size_t)h * 64 * SEQ;

    bf16x8 bq[2];
    {
        const unsigned short* qrow = qh + (size_t)(i0 + w * 16 + lr) * 64 + lg * 8;
        bq[0] = *(const bf16x8*)qrow;
        bq[1] = *(const bf16x8*)(qrow + 32);
    }

    f32x4 accO[4];
    #pragma unroll
    for (int n = 0; n < 4; ++n) accO[n] = f32x4{0.f, 0.f, 0.f, 0.f};
    float lsum = 0.0f;
    const int iq = i0 + w * 16 + lr;

    for (int c = 0; c < 5; ++c) {
        const int j0 = i0 - WIN + c * 64;
        if (j0 < 0 || j0 >= SEQ) continue;

        bf16x8 ak[2][4];
        #pragma unroll
        for (int m = 0; m < 4; ++m) {
            const unsigned short* kr = kh + (size_t)(j0 + m * 16 + lr) * 64 + lg * 8;
            ak[0][m] = *(const bf16x8*)kr;
            ak[1][m] = *(const bf16x8*)(kr + 32);
        }
        bf16x8 bv[2][4];
        #pragma unroll
        for (int n = 0; n < 4; ++n) {
            const unsigned short* vr = vh + (size_t)(n * 16 + lr) * SEQ + j0 + lg * 8;
            bv[0][n] = *(const bf16x8*)vr;
            bv[1][n] = *(const bf16x8*)(vr + 32);
        }

        f32x4 accS[4];
        #pragma unroll
        for (int m = 0; m < 4; ++m) {
            accS[m] = f32x4{0.f, 0.f, 0.f, 0.f};
            #pragma unroll
            for (int s = 0; s < 2; ++s)
                accS[m] = __builtin_amdgcn_mfma_f32_16x16x32_bf16(
                    ak[s][m], bq[s], accS[m], 0, 0, 0);
        }

        #pragma unroll
        for (int m = 0; m < 4; ++m) {
            const int kbase = j0 + m * 16 + lg * 4;
            float p0, p1, p2, p3;
            {
                int d0 = kbase + 0 - iq; bool v0 = (d0 >= -WIN) && (d0 <= WIN);
                int d1 = kbase + 1 - iq; bool v1 = (d1 >= -WIN) && (d1 <= WIN);
                int d2 = kbase + 2 - iq; bool v2 = (d2 >= -WIN) && (d2 <= WIN);
                int d3 = kbase + 3 - iq; bool v3 = (d3 >= -WIN) && (d3 <= WIN);
                p0 = v0 ? exp2f(accS[m][0] * SCALE_L2E) : 0.0f;
                p1 = v1 ? exp2f(accS[m][1] * SCALE_L2E) : 0.0f;
                p2 = v2 ? exp2f(accS[m][2] * SCALE_L2E) : 0.0f;
                p3 = v3 ? exp2f(accS[m][3] * SCALE_L2E) : 0.0f;
            }
            lsum += (p0 + p1) + (p2 + p3);
            ushort4 pk = make_ushort4(f2bf(p0), f2bf(p1), f2bf(p2), f2bf(p3));
            *(ushort4*)&P_lds[w][lr][m * 16 + lg * 4] = pk;
        }

        bf16x8 pa[2];
        pa[0] = *(const bf16x8*)&P_lds[w][lr][lg * 8];
        pa[1] = *(const bf16x8*)&P_lds[w][lr][32 + lg * 8];

        #pragma unroll
        for (int n = 0; n < 4; ++n)
            #pragma unroll
            for (int s = 0; s < 2; ++s)
                accO[n] = __builtin_amdgcn_mfma_f32_16x16x32_bf16(
                    pa[s], bv[s][n], accO[n], 0, 0, 0);
    }

    lsum += __shfl_xor(lsum, 16, 64);
    lsum += __shfl_xor(lsum, 32, 64);
    float rinv[4];
    #pragma unroll
    for (int j = 0; j < 4; ++j)
        rinv[j] = 1.0f / __shfl(lsum, lg * 4 + j, 64);

    #pragma unroll
    for (int n = 0; n < 4; ++n)
        #pragma unroll
        for (int j = 0; j < 4; ++j) {
            int row = i0 + w * 16 + lg * 4 + j;
            int col = h * 64 + n * 16 + lr;
            o[(size_t)row * D + col] = f2bf(accO[n][j] * rinv[j]);
        }
}

// ---------------------------------------------------------------------------
// out = LayerNorm(residual + sum_{p<NP} P_bf16[p]) * g + beta.
// ---------------------------------------------------------------------------
template <int NP, bool RES_BF16, bool OUT_BF16>
__global__ __launch_bounds__(256) void add_ln(
    const void* __restrict__ res, const unsigned short* __restrict__ P,
    size_t pstride,
    const float* __restrict__ g, const float* __restrict__ beta,
    void* __restrict__ out)
{
    const int wave = threadIdx.x >> 6;
    const int lane = threadIdx.x & 63;
    const int row = blockIdx.x * 4 + wave;
    const size_t rbase = (size_t)row * D;

    float v[8];
    float sum = 0.0f, sumsq = 0.0f;
    #pragma unroll
    for (int e = 0; e < 8; ++e) {
        int c = lane + e * 64;
        float z = RES_BF16 ? bf2f(((const unsigned short*)res)[rbase + c])
                           : ((const float*)res)[rbase + c];
        #pragma unroll
        for (int p = 0; p < NP; ++p)
            z += bf2f(P[p * pstride + rbase + c]);
        v[e] = z;
        sum += z;
        sumsq += z * z;
    }
    #pragma unroll
    for (int off = 32; off; off >>= 1) {
        sum   += __shfl_xor(sum, off, 64);
        sumsq += __shfl_xor(sumsq, off, 64);
    }
    const float mu   = sum * (1.0f / D);
    const float var  = sumsq * (1.0f / D) - mu * mu;
    const float rstd = rsqrtf(var + LN_EPS);

    #pragma unroll
    for (int e = 0; e < 8; ++e) {
        int c = lane + e * 64;
        float r = (v[e] - mu) * rstd * g[c] + beta[c];
        if (OUT_BF16) ((unsigned short*)out)[rbase + c] = f2bf(r);
        else          ((float*)out)[rbase + c] = r;
    }
}

// ---------------------------------------------------------------------------
extern "C" void kernel_launch(void* const* d_in, const int* in_sizes, int n_in,
                              void* d_out, int out_size, void* d_ws, size_t ws_size,
                              hipStream_t stream)
{
    const float* x      = (const float*)d_in[0];
    const float* qkv_w  = (const float*)d_in[1];
    const float* qkv_b  = (const float*)d_in[2];
    const float* out_w  = (const float*)d_in[3];
    const float* out_b  = (const float*)d_in[4];
    const float* ln1_g  = (const float*)d_in[5];
    const float* ln1_b  = (const float*)d_in[6];
    const float* w1     = (const float*)d_in[7];
    const float* b1     = (const float*)d_in[8];
    const float* w2     = (const float*)d_in[9];
    const float* b2     = (const float*)d_in[10];
    const float* ln2_g  = (const float*)d_in[11];
    const float* ln2_b  = (const float*)d_in[12];
    float* out = (float*)d_out;

    // ---- workspace layout (flat, no aliasing; 70 MiB total) ----
    constexpr size_t MiB = 1u << 20;
    char* base = (char*)d_ws;
    unsigned short* xb     = (unsigned short*)(base + 0);                     // 4
    unsigned short* qkvw_t = (unsigned short*)(base + 4 * MiB);               // 1.5
    unsigned short* outw_t = (unsigned short*)(base + 5 * MiB + 512 * 1024);  // 0.5
    unsigned short* w1_t   = (unsigned short*)(base + 6 * MiB);               // 2
    unsigned short* w2_t   = (unsigned short*)(base + 8 * MiB);               // 2
    unsigned short* qbuf   = (unsigned short*)(base + 10 * MiB);              // 4
    unsigned short* kbuf   = (unsigned short*)(base + 14 * MiB);              // 4
    unsigned short* vtbuf  = (unsigned short*)(base + 18 * MiB);              // 4
    unsigned short* o_b    = (unsigned short*)(base + 22 * MiB);              // 4
    unsigned short* pOut   = (unsigned short*)(base + 26 * MiB);              // 8  (2 partials)
    unsigned short* x1b    = (unsigned short*)(base + 34 * MiB);              // 4
    unsigned short* ff1b   = (unsigned short*)(base + 38 * MiB);              // 16
    unsigned short* pFF2   = (unsigned short*)(base + 54 * MiB);              // 16 (4 partials)

    // 0) conversions + weight transposes (one kernel)
    prep<<<4096, 256, 0, stream>>>(x, xb, qkv_w, out_w, w1, w2,
                                   qkvw_t, outw_t, w1_t, w2_t);

    // 1) qkv projection -> qb/kb/vtb (8-wave 2-phase dbuf)
    gemm_qkv<<<dim3(3 * D / 128, SEQ / 128), 512, 0, stream>>>(
        xb, qkvw_t, qkv_b, qbuf, kbuf, vtbuf);

    // 2) MFMA windowed attention -> o bf16
    attn_mfma<<<dim3(SEQ / 64, NH), 256, 0, stream>>>(qbuf, kbuf, vtbuf, o_b);

    // 3) out-proj, split-K 2 -> bf16 partials
    gemm_splitk<<<dim3(D / 128, SEQ / 128, 2), 512, 0, stream>>>(
        o_b, outw_t, out_b, pOut, SEQ, D, D, D / 2);

    // 4) x1b = bf16( LN(x + p0 + p1) )
    add_ln<2, false, true><<<SEQ / 4, 256, 0, stream>>>(
        x, pOut, (size_t)SEQ * D, ln1_g, ln1_b, x1b);

    // 5) ff1 = relu(x1b @ w1 + b1) -> bf16
    gemm_mfma<true, true><<<dim3(DFF / 128, SEQ / 128), 512, 0, stream>>>(
        x1b, w1_t, b1, ff1b, SEQ, DFF, D);

    // 6) ff2 split-K 4 -> bf16 partials
    gemm_splitk<<<dim3(D / 128, SEQ / 128, 4), 512, 0, stream>>>(
        ff1b, w2_t, b2, pFF2, SEQ, D, DFF, DFF / 4);

    // 7) out = LN(x1b + p0+p1+p2+p3) -> fp32
    add_ln<4, true, false><<<SEQ / 4, 256, 0, stream>>>(
        x1b, pFF2, (size_t)SEQ * D, ln2_g, ln2_b, out);
}

// Round 10
// 90.850 us; speedup vs baseline: 1.1451x; 1.0524x over previous
//
#include <hip/hip_runtime.h>
#include <math.h>

// Problem constants
constexpr int D      = 512;
constexpr int NH     = 8;
constexpr int HD     = 64;
constexpr int WIN    = 128;
constexpr int DFF    = 2048;
constexpr int SEQ    = 4096;
constexpr float LN_EPS = 1e-5f;

typedef float f32x4 __attribute__((ext_vector_type(4)));
typedef __bf16 bf16x8 __attribute__((ext_vector_type(8)));

__device__ __forceinline__ unsigned short f2bf(float f) {
    union { float f; unsigned u; } v; v.f = f;
    unsigned r = v.u + 0x7FFF + ((v.u >> 16) & 1);   // round-to-nearest-even
    return (unsigned short)(r >> 16);
}
__device__ __forceinline__ float bf2f(unsigned short u) {
    union { unsigned u; float f; } v; v.u = (unsigned)u << 16; return v.f;
}

__device__ __forceinline__ void gload16(const void* g, void* l) {
    __builtin_amdgcn_global_load_lds(
        (const __attribute__((address_space(1))) unsigned int*)g,
        (__attribute__((address_space(3))) unsigned int*)l,
        16, 0, 0);
}

// XCD-chunked bijective blockIdx swizzle (T1). Requires nwg % 8 == 0.
// HW round-robins linear block id across 8 XCDs; this remap gives each XCD a
// CONTIGUOUS chunk of work ids so neighboring tiles share its private L2.
// Returns work id; caller decodes (bx, by, bz).
__device__ __forceinline__ int xcd_swizzle() {
    const int orig = blockIdx.x + gridDim.x * (blockIdx.y + gridDim.y * blockIdx.z);
    const int nwg  = gridDim.x * gridDim.y * gridDim.z;
    return (orig & 7) * (nwg >> 3) + (orig >> 3);
}

// ---------------------------------------------------------------------------
// prep: block [0,1024)  : x fp32 -> xb bf16 (2048 elems/block)
//       block [1024,4096): weight transposes W[K][N] fp32 -> Wt[N][K] bf16
// ---------------------------------------------------------------------------
__global__ __launch_bounds__(256) void prep(
    const float* __restrict__ x, unsigned short* __restrict__ xb,
    const float* __restrict__ qkv_w, const float* __restrict__ out_w,
    const float* __restrict__ w1,    const float* __restrict__ w2,
    unsigned short* __restrict__ qkvw_t, unsigned short* __restrict__ outw_t,
    unsigned short* __restrict__ w1_t,   unsigned short* __restrict__ w2_t)
{
    const int b = blockIdx.x;
    if (b < 1024) {
        int i = b * 2048 + threadIdx.x * 8;
        float4 v0 = *(const float4*)(x + i);
        float4 v1 = *(const float4*)(x + i + 4);
        ushort4 u0 = make_ushort4(f2bf(v0.x), f2bf(v0.y), f2bf(v0.z), f2bf(v0.w));
        ushort4 u1 = make_ushort4(f2bf(v1.x), f2bf(v1.y), f2bf(v1.z), f2bf(v1.w));
        *(ushort4*)(xb + i) = u0;
        *(ushort4*)(xb + i + 4) = u1;
        return;
    }
    __shared__ float t[32][33];
    const int b2 = b - 1024;
    const float* W; unsigned short* Wt; int K, N, nt, kt;
    if (b2 < 768)       { W = qkv_w; Wt = qkvw_t; K = 512;  N = 1536; nt = b2 % 48;          kt = b2 / 48; }
    else if (b2 < 1024) { W = out_w; Wt = outw_t; K = 512;  N = 512;  nt = (b2 - 768) % 16;  kt = (b2 - 768) / 16; }
    else if (b2 < 2048) { W = w1;    Wt = w1_t;   K = 512;  N = 2048; nt = (b2 - 1024) % 64; kt = (b2 - 1024) / 64; }
    else                { W = w2;    Wt = w2_t;   K = 2048; N = 512;  nt = (b2 - 2048) % 16; kt = (b2 - 2048) / 16; }
    const int tx = threadIdx.x & 31, ty = threadIdx.x >> 5;
    const int n0 = nt * 32, k0 = kt * 32;
    #pragma unroll
    for (int r = 0; r < 4; ++r)
        t[ty + r * 8][tx] = W[(size_t)(k0 + ty + r * 8) * N + n0 + tx];
    __syncthreads();
    #pragma unroll
    for (int r = 0; r < 4; ++r)
        Wt[(size_t)(n0 + ty + r * 8) * K + k0 + tx] = f2bf(t[tx][ty + r * 8]);
}

// ---------------------------------------------------------------------------
// Stage one BK=64 tile with 512 threads (1 gload16 per thread per quarter):
// LDS buf layout: Ah0 [0,8K) | Ah1 [8K,16K) | Bh0 [16K,24K) | Bh1 [24K,32K),
// each half = [128 rows][64B].
// ---------------------------------------------------------------------------
__device__ __forceinline__ void stage64_8w(
    const unsigned short* __restrict__ A, const unsigned short* __restrict__ Bt,
    int K, int m0, int n0, int k0, char* buf, int tid)
{
    const int row = tid >> 2;          // 0..127
    const int kb  = (tid & 3) * 16;    // byte within 64B half-row
    const char* pa = (const char*)A  + ((size_t)(m0 + row) * K + k0) * 2 + kb;
    const char* pb = (const char*)Bt + ((size_t)(n0 + row) * K + k0) * 2 + kb;
    char* dst = buf + tid * 16;        // == row*64 + kb
    gload16(pa,      dst);
    gload16(pa + 64, dst + 8192);
    gload16(pb,      dst + 16384);
    gload16(pb + 64, dst + 24576);
}

// ---------------------------------------------------------------------------
// GEMM core, 8 waves (512 thr), 128x128 tile, BK=64, 2-phase double buffer.
// Wave wv = (wr=wv>>2, wc=wv&3) owns a 64x32 sub-tile: 4 m-frags x 2 n-frags.
// 16 waves/CU when 2 blocks co-reside.
// ---------------------------------------------------------------------------
__device__ __forceinline__ void gemm_core_db8(
    const unsigned short* __restrict__ A, const unsigned short* __restrict__ Bt,
    int K, int m0, int n0, int kbeg, int kend, char* lds, f32x4 acc[4][2])
{
    const int tid  = threadIdx.x;
    const int lane = tid & 63;
    const int wave = tid >> 6;            // 0..7
    const int wr = wave >> 2, wc = wave & 3;
    const int lr = lane & 15, lk = lane >> 4;
    const int aoff = ((wr * 64 + lr) << 6) + (lk << 4);
    const int boff = 16384 + ((wc * 32 + lr) << 6) + (lk << 4);

    stage64_8w(A, Bt, K, m0, n0, kbeg, lds, tid);
    __syncthreads();

    int cur = 0;
    for (int k0 = kbeg; k0 < kend; k0 += 64) {
        char* bufc = lds + cur * 32768;
        if (k0 + 64 < kend)
            stage64_8w(A, Bt, K, m0, n0, k0 + 64, lds + (cur ^ 1) * 32768, tid);

        bf16x8 af[2][4], bfv[2][2];
        #pragma unroll
        for (int m = 0; m < 4; ++m) {
            af[0][m] = *(const bf16x8*)(bufc +        aoff + m * 1024);
            af[1][m] = *(const bf16x8*)(bufc + 8192 + aoff + m * 1024);
        }
        #pragma unroll
        for (int n = 0; n < 2; ++n) {
            bfv[0][n] = *(const bf16x8*)(bufc +        boff + n * 1024);
            bfv[1][n] = *(const bf16x8*)(bufc + 8192 + boff + n * 1024);
        }
        #pragma unroll
        for (int ks = 0; ks < 2; ++ks)
            #pragma unroll
            for (int m = 0; m < 4; ++m)
                #pragma unroll
                for (int n = 0; n < 2; ++n)
                    acc[m][n] = __builtin_amdgcn_mfma_f32_16x16x32_bf16(
                        af[ks][m], bfv[ks][n], acc[m][n], 0, 0, 0);

        __syncthreads();   // drains this iter's prefetch; buf swap safe
        cur ^= 1;
    }
}

// ---------------------------------------------------------------------------
// Monolithic GEMM + bias (+ReLU), bf16 or fp32 out. 128x128 tile, 8 waves.
// ---------------------------------------------------------------------------
template <bool RELU, bool OUT_BF16>
__global__ __launch_bounds__(512) void gemm_mfma(
    const unsigned short* __restrict__ A,
    const unsigned short* __restrict__ Bt,
    const float* __restrict__ bias,
    void* __restrict__ Cv, int M, int N, int K)
{
    __shared__ __align__(16) char lds[65536];
    const int lane = threadIdx.x & 63;
    const int wave = threadIdx.x >> 6;
    const int wr = wave >> 2, wc = wave & 3;
    const int lr = lane & 15, lk = lane >> 4;

    const int wg = xcd_swizzle();
    const int bx = wg % gridDim.x, by = wg / gridDim.x;
    const int m0 = by * 128, n0 = bx * 128;

    f32x4 acc[4][2];
    #pragma unroll
    for (int m = 0; m < 4; ++m)
        #pragma unroll
        for (int n = 0; n < 2; ++n) acc[m][n] = f32x4{0.f, 0.f, 0.f, 0.f};

    gemm_core_db8(A, Bt, K, m0, n0, 0, K, lds, acc);

    const int col0 = n0 + wc * 32 + lr;
    const int row0 = m0 + wr * 64 + lk * 4;
    #pragma unroll
    for (int m = 0; m < 4; ++m)
        #pragma unroll
        for (int n = 0; n < 2; ++n) {
            int col = col0 + n * 16;
            float bv = bias[col];
            #pragma unroll
            for (int j = 0; j < 4; ++j) {
                int row = row0 + m * 16 + j;
                float v = acc[m][n][j] + bv;
                if (RELU) v = fmaxf(v, 0.0f);
                if (OUT_BF16)
                    ((unsigned short*)Cv)[(size_t)row * N + col] = f2bf(v);
                else
                    ((float*)Cv)[(size_t)row * N + col] = v;
            }
        }
}

// ---------------------------------------------------------------------------
// Split-K GEMM: chunk z covers [z*Kc,(z+1)*Kc); writes bf16 partial to
// P + z*M*N (bias folded into chunk 0). Combined in the following add_ln.
// ---------------------------------------------------------------------------
__global__ __launch_bounds__(512) void gemm_splitk(
    const unsigned short* __restrict__ A,
    const unsigned short* __restrict__ Bt,
    const float* __restrict__ bias,
    unsigned short* __restrict__ P, int M, int N, int K, int Kc)
{
    __shared__ __align__(16) char lds[65536];
    const int lane = threadIdx.x & 63;
    const int wave = threadIdx.x >> 6;
    const int wr = wave >> 2, wc = wave & 3;
    const int lr = lane & 15, lk = lane >> 4;

    const int wg = xcd_swizzle();
    const int bx = wg % gridDim.x;
    const int tmp = wg / gridDim.x;
    const int by = tmp % gridDim.y;
    const int zc = tmp / gridDim.y;
    const int m0 = by * 128, n0 = bx * 128;

    f32x4 acc[4][2];
    #pragma unroll
    for (int m = 0; m < 4; ++m)
        #pragma unroll
        for (int n = 0; n < 2; ++n) acc[m][n] = f32x4{0.f, 0.f, 0.f, 0.f};

    gemm_core_db8(A, Bt, K, m0, n0, zc * Kc, zc * Kc + Kc, lds, acc);

    unsigned short* Cp = P + (size_t)zc * M * N;
    const int col0 = n0 + wc * 32 + lr;
    const int row0 = m0 + wr * 64 + lk * 4;
    #pragma unroll
    for (int m = 0; m < 4; ++m)
        #pragma unroll
        for (int n = 0; n < 2; ++n) {
            int col = col0 + n * 16;
            float bv = (zc == 0) ? bias[col] : 0.0f;
            #pragma unroll
            for (int j = 0; j < 4; ++j) {
                int row = row0 + m * 16 + j;
                Cp[(size_t)row * N + col] = f2bf(acc[m][n][j] + bv);
            }
        }
}

// ---------------------------------------------------------------------------
// QKV GEMM: attention-layout epilogue. qb/kb [NH][SEQ][64], vtb [NH][64][SEQ].
// ---------------------------------------------------------------------------
__global__ __launch_bounds__(512) void gemm_qkv(
    const unsigned short* __restrict__ A,
    const unsigned short* __restrict__ Bt,
    const float* __restrict__ bias,
    unsigned short* __restrict__ qb,
    unsigned short* __restrict__ kb,
    unsigned short* __restrict__ vtb)
{
    constexpr int N = 3 * D, K = D;
    __shared__ __align__(16) char lds[65536];
    const int lane = threadIdx.x & 63;
    const int wave = threadIdx.x >> 6;
    const int wr = wave >> 2, wc = wave & 3;
    const int lr = lane & 15, lk = lane >> 4;

    const int wg = xcd_swizzle();
    const int bx = wg % gridDim.x, by = wg / gridDim.x;
    const int m0 = by * 128, n0 = bx * 128;

    f32x4 acc[4][2];
    #pragma unroll
    for (int m = 0; m < 4; ++m)
        #pragma unroll
        for (int n = 0; n < 2; ++n) acc[m][n] = f32x4{0.f, 0.f, 0.f, 0.f};

    gemm_core_db8(A, Bt, K, m0, n0, 0, K, lds, acc);

    const int col0 = n0 + wc * 32 + lr;
    const int row0 = m0 + wr * 64 + lk * 4;
    const int region = n0 >> 9;   // 0=Q, 1=K, 2=V (uniform per block)
    #pragma unroll
    for (int m = 0; m < 4; ++m)
        #pragma unroll
        for (int n = 0; n < 2; ++n) {
            const int col = col0 + n * 16;
            const float bv = bias[col];
            const int rowm = row0 + m * 16;
            if (region == 2) {
                const int cc = col - 1024, hh = cc >> 6, dd = cc & 63;
                ushort4 u = make_ushort4(f2bf(acc[m][n][0] + bv),
                                         f2bf(acc[m][n][1] + bv),
                                         f2bf(acc[m][n][2] + bv),
                                         f2bf(acc[m][n][3] + bv));
                *(ushort4*)&vtb[((size_t)(hh * 64 + dd)) * SEQ + rowm] = u;
            } else {
                const int cc = col - region * 512, hh = cc >> 6, dd = cc & 63;
                unsigned short* dst = (region == 0) ? qb : kb;
                #pragma unroll
                for (int j = 0; j < 4; ++j)
                    dst[((size_t)hh * SEQ + rowm + j) * 64 + dd] =
                        f2bf(acc[m][n][j] + bv);
            }
        }
}

// ---------------------------------------------------------------------------
// MFMA windowed attention. Swizzled so XCD k owns head k entirely (nwg/8 = 64
// = tiles per head): K/V (2MB/head) stays in one XCD's L2, tiles sequential.
// ---------------------------------------------------------------------------
__global__ __launch_bounds__(256) void attn_mfma(
    const unsigned short* __restrict__ qb,
    const unsigned short* __restrict__ kb,
    const unsigned short* __restrict__ vtb,
    unsigned short* __restrict__ o)
{
    constexpr float SCALE_L2E = 0.044194173824159216f * 1.4426950408889634f;
    __shared__ __align__(16) unsigned short P_lds[4][16][72];

    const int lane = threadIdx.x & 63;
    const int w    = threadIdx.x >> 6;

    const int wg = xcd_swizzle();          // nwg = 512
    const int i0 = (wg & 63) * 64;         // tile
    const int h  = wg >> 6;                // head
    const int lr = lane & 15, lg = lane >> 4;

    const unsigned short* qh = qb  + (size_t)h * SEQ * 64;
    const unsigned short* kh = kb  + (size_t)h * SEQ * 64;
    const unsigned short* vh = vtb + (size_t)h * 64 * SEQ;

    bf16x8 bq[2];
    {
        const unsigned short* qrow = qh + (size_t)(i0 + w * 16 + lr) * 64 + lg * 8;
        bq[0] = *(const bf16x8*)qrow;
        bq[1] = *(const bf16x8*)(qrow + 32);
    }

    f32x4 accO[4];
    #pragma unroll
    for (int n = 0; n < 4; ++n) accO[n] = f32x4{0.f, 0.f, 0.f, 0.f};
    float lsum = 0.0f;
    const int iq = i0 + w * 16 + lr;

    for (int c = 0; c < 5; ++c) {
        const int j0 = i0 - WIN + c * 64;
        if (j0 < 0 || j0 >= SEQ) continue;

        bf16x8 ak[2][4];
        #pragma unroll
        for (int m = 0; m < 4; ++m) {
            const unsigned short* kr = kh + (size_t)(j0 + m * 16 + lr) * 64 + lg * 8;
            ak[0][m] = *(const bf16x8*)kr;
            ak[1][m] = *(const bf16x8*)(kr + 32);
        }
        bf16x8 bv[2][4];
        #pragma unroll
        for (int n = 0; n < 4; ++n) {
            const unsigned short* vr = vh + (size_t)(n * 16 + lr) * SEQ + j0 + lg * 8;
            bv[0][n] = *(const bf16x8*)vr;
            bv[1][n] = *(const bf16x8*)(vr + 32);
        }

        f32x4 accS[4];
        #pragma unroll
        for (int m = 0; m < 4; ++m) {
            accS[m] = f32x4{0.f, 0.f, 0.f, 0.f};
            #pragma unroll
            for (int s = 0; s < 2; ++s)
                accS[m] = __builtin_amdgcn_mfma_f32_16x16x32_bf16(
                    ak[s][m], bq[s], accS[m], 0, 0, 0);
        }

        #pragma unroll
        for (int m = 0; m < 4; ++m) {
            const int kbase = j0 + m * 16 + lg * 4;
            float p0, p1, p2, p3;
            {
                int d0 = kbase + 0 - iq; bool v0 = (d0 >= -WIN) && (d0 <= WIN);
                int d1 = kbase + 1 - iq; bool v1 = (d1 >= -WIN) && (d1 <= WIN);
                int d2 = kbase + 2 - iq; bool v2 = (d2 >= -WIN) && (d2 <= WIN);
                int d3 = kbase + 3 - iq; bool v3 = (d3 >= -WIN) && (d3 <= WIN);
                p0 = v0 ? exp2f(accS[m][0] * SCALE_L2E) : 0.0f;
                p1 = v1 ? exp2f(accS[m][1] * SCALE_L2E) : 0.0f;
                p2 = v2 ? exp2f(accS[m][2] * SCALE_L2E) : 0.0f;
                p3 = v3 ? exp2f(accS[m][3] * SCALE_L2E) : 0.0f;
            }
            lsum += (p0 + p1) + (p2 + p3);
            ushort4 pk = make_ushort4(f2bf(p0), f2bf(p1), f2bf(p2), f2bf(p3));
            *(ushort4*)&P_lds[w][lr][m * 16 + lg * 4] = pk;
        }

        bf16x8 pa[2];
        pa[0] = *(const bf16x8*)&P_lds[w][lr][lg * 8];
        pa[1] = *(const bf16x8*)&P_lds[w][lr][32 + lg * 8];

        #pragma unroll
        for (int n = 0; n < 4; ++n)
            #pragma unroll
            for (int s = 0; s < 2; ++s)
                accO[n] = __builtin_amdgcn_mfma_f32_16x16x32_bf16(
                    pa[s], bv[s][n], accO[n], 0, 0, 0);
    }

    lsum += __shfl_xor(lsum, 16, 64);
    lsum += __shfl_xor(lsum, 32, 64);
    float rinv[4];
    #pragma unroll
    for (int j = 0; j < 4; ++j)
        rinv[j] = 1.0f / __shfl(lsum, lg * 4 + j, 64);

    #pragma unroll
    for (int n = 0; n < 4; ++n)
        #pragma unroll
        for (int j = 0; j < 4; ++j) {
            int row = i0 + w * 16 + lg * 4 + j;
            int col = h * 64 + n * 16 + lr;
            o[(size_t)row * D + col] = f2bf(accO[n][j] * rinv[j]);
        }
}

// ---------------------------------------------------------------------------
// out = LayerNorm(residual + sum_{p<NP} P_bf16[p]) * g + beta.
// ---------------------------------------------------------------------------
template <int NP, bool RES_BF16, bool OUT_BF16>
__global__ __launch_bounds__(256) void add_ln(
    const void* __restrict__ res, const unsigned short* __restrict__ P,
    size_t pstride,
    const float* __restrict__ g, const float* __restrict__ beta,
    void* __restrict__ out)
{
    const int wave = threadIdx.x >> 6;
    const int lane = threadIdx.x & 63;
    const int row = blockIdx.x * 4 + wave;
    const size_t rbase = (size_t)row * D;

    float v[8];
    float sum = 0.0f, sumsq = 0.0f;
    #pragma unroll
    for (int e = 0; e < 8; ++e) {
        int c = lane + e * 64;
        float z = RES_BF16 ? bf2f(((const unsigned short*)res)[rbase + c])
                           : ((const float*)res)[rbase + c];
        #pragma unroll
        for (int p = 0; p < NP; ++p)
            z += bf2f(P[p * pstride + rbase + c]);
        v[e] = z;
        sum += z;
        sumsq += z * z;
    }
    #pragma unroll
    for (int off = 32; off; off >>= 1) {
        sum   += __shfl_xor(sum, off, 64);
        sumsq += __shfl_xor(sumsq, off, 64);
    }
    const float mu   = sum * (1.0f / D);
    const float var  = sumsq * (1.0f / D) - mu * mu;
    const float rstd = rsqrtf(var + LN_EPS);

    #pragma unroll
    for (int e = 0; e < 8; ++e) {
        int c = lane + e * 64;
        float r = (v[e] - mu) * rstd * g[c] + beta[c];
        if (OUT_BF16) ((unsigned short*)out)[rbase + c] = f2bf(r);
        else          ((float*)out)[rbase + c] = r;
    }
}

// ---------------------------------------------------------------------------
extern "C" void kernel_launch(void* const* d_in, const int* in_sizes, int n_in,
                              void* d_out, int out_size, void* d_ws, size_t ws_size,
                              hipStream_t stream)
{
    const float* x      = (const float*)d_in[0];
    const float* qkv_w  = (const float*)d_in[1];
    const float* qkv_b  = (const float*)d_in[2];
    const float* out_w  = (const float*)d_in[3];
    const float* out_b  = (const float*)d_in[4];
    const float* ln1_g  = (const float*)d_in[5];
    const float* ln1_b  = (const float*)d_in[6];
    const float* w1     = (const float*)d_in[7];
    const float* b1     = (const float*)d_in[8];
    const float* w2     = (const float*)d_in[9];
    const float* b2     = (const float*)d_in[10];
    const float* ln2_g  = (const float*)d_in[11];
    const float* ln2_b  = (const float*)d_in[12];
    float* out = (float*)d_out;

    // ---- workspace layout (flat, no aliasing; 70 MiB total) ----
    constexpr size_t MiB = 1u << 20;
    char* base = (char*)d_ws;
    unsigned short* xb     = (unsigned short*)(base + 0);                     // 4
    unsigned short* qkvw_t = (unsigned short*)(base + 4 * MiB);               // 1.5
    unsigned short* outw_t = (unsigned short*)(base + 5 * MiB + 512 * 1024);  // 0.5
    unsigned short* w1_t   = (unsigned short*)(base + 6 * MiB);               // 2
    unsigned short* w2_t   = (unsigned short*)(base + 8 * MiB);               // 2
    unsigned short* qbuf   = (unsigned short*)(base + 10 * MiB);              // 4
    unsigned short* kbuf   = (unsigned short*)(base + 14 * MiB);              // 4
    unsigned short* vtbuf  = (unsigned short*)(base + 18 * MiB);              // 4
    unsigned short* o_b    = (unsigned short*)(base + 22 * MiB);              // 4
    unsigned short* pOut   = (unsigned short*)(base + 26 * MiB);              // 8  (2 partials)
    unsigned short* x1b    = (unsigned short*)(base + 34 * MiB);              // 4
    unsigned short* ff1b   = (unsigned short*)(base + 38 * MiB);              // 16
    unsigned short* pFF2   = (unsigned short*)(base + 54 * MiB);              // 16 (4 partials)

    // 0) conversions + weight transposes (one kernel)
    prep<<<4096, 256, 0, stream>>>(x, xb, qkv_w, out_w, w1, w2,
                                   qkvw_t, outw_t, w1_t, w2_t);

    // 1) qkv projection -> qb/kb/vtb (8-wave 2-phase dbuf, XCD-swizzled)
    gemm_qkv<<<dim3(3 * D / 128, SEQ / 128), 512, 0, stream>>>(
        xb, qkvw_t, qkv_b, qbuf, kbuf, vtbuf);

    // 2) MFMA windowed attention -> o bf16 (XCD-swizzled: head per XCD)
    attn_mfma<<<dim3(SEQ / 64, NH), 256, 0, stream>>>(qbuf, kbuf, vtbuf, o_b);

    // 3) out-proj, split-K 2 -> bf16 partials
    gemm_splitk<<<dim3(D / 128, SEQ / 128, 2), 512, 0, stream>>>(
        o_b, outw_t, out_b, pOut, SEQ, D, D, D / 2);

    // 4) x1b = bf16( LN(x + p0 + p1) )
    add_ln<2, false, true><<<SEQ / 4, 256, 0, stream>>>(
        x, pOut, (size_t)SEQ * D, ln1_g, ln1_b, x1b);

    // 5) ff1 = relu(x1b @ w1 + b1) -> bf16
    gemm_mfma<true, true><<<dim3(DFF / 128, SEQ / 128), 512, 0, stream>>>(
        x1b, w1_t, b1, ff1b, SEQ, DFF, D);

    // 6) ff2 split-K 4 -> bf16 partials
    gemm_splitk<<<dim3(D / 128, SEQ / 128, 4), 512, 0, stream>>>(
        ff1b, w2_t, b2, pFF2, SEQ, D, DFF, DFF / 4);

    // 7) out = LN(x1b + p0+p1+p2+p3) -> fp32
    add_ln<4, true, false><<<SEQ / 4, 256, 0, stream>>>(
        x1b, pFF2, (size_t)SEQ * D, ln2_g, ln2_b, out);
}

// Round 11
// 90.523 us; speedup vs baseline: 1.1493x; 1.0036x over previous
//
#include <hip/hip_runtime.h>
#include <math.h>

// Problem constants
constexpr int D      = 512;
constexpr int NH     = 8;
constexpr int HD     = 64;
constexpr int WIN    = 128;
constexpr int DFF    = 2048;
constexpr int SEQ    = 4096;
constexpr float LN_EPS = 1e-5f;

typedef float f32x4 __attribute__((ext_vector_type(4)));
typedef __bf16 bf16x8 __attribute__((ext_vector_type(8)));

__device__ __forceinline__ unsigned short f2bf(float f) {
    union { float f; unsigned u; } v; v.f = f;
    unsigned r = v.u + 0x7FFF + ((v.u >> 16) & 1);   // round-to-nearest-even
    return (unsigned short)(r >> 16);
}
__device__ __forceinline__ float bf2f(unsigned short u) {
    union { unsigned u; float f; } v; v.u = (unsigned)u << 16; return v.f;
}

__device__ __forceinline__ void gload16(const void* g, void* l) {
    __builtin_amdgcn_global_load_lds(
        (const __attribute__((address_space(1))) unsigned int*)g,
        (__attribute__((address_space(3))) unsigned int*)l,
        16, 0, 0);
}

// XCD-chunked bijective blockIdx swizzle (T1). Requires nwg % 8 == 0.
__device__ __forceinline__ int xcd_swizzle() {
    const int orig = blockIdx.x + gridDim.x * (blockIdx.y + gridDim.y * blockIdx.z);
    const int nwg  = gridDim.x * gridDim.y * gridDim.z;
    return (orig & 7) * (nwg >> 3) + (orig >> 3);
}

// ---------------------------------------------------------------------------
// prep: block [0,1024)  : x fp32 -> xb bf16 (2048 elems/block)
//       block [1024,4096): weight transposes W[K][N] fp32 -> Wt[N][K] bf16
// ---------------------------------------------------------------------------
__global__ __launch_bounds__(256) void prep(
    const float* __restrict__ x, unsigned short* __restrict__ xb,
    const float* __restrict__ qkv_w, const float* __restrict__ out_w,
    const float* __restrict__ w1,    const float* __restrict__ w2,
    unsigned short* __restrict__ qkvw_t, unsigned short* __restrict__ outw_t,
    unsigned short* __restrict__ w1_t,   unsigned short* __restrict__ w2_t)
{
    const int b = blockIdx.x;
    if (b < 1024) {
        int i = b * 2048 + threadIdx.x * 8;
        float4 v0 = *(const float4*)(x + i);
        float4 v1 = *(const float4*)(x + i + 4);
        ushort4 u0 = make_ushort4(f2bf(v0.x), f2bf(v0.y), f2bf(v0.z), f2bf(v0.w));
        ushort4 u1 = make_ushort4(f2bf(v1.x), f2bf(v1.y), f2bf(v1.z), f2bf(v1.w));
        *(ushort4*)(xb + i) = u0;
        *(ushort4*)(xb + i + 4) = u1;
        return;
    }
    __shared__ float t[32][33];
    const int b2 = b - 1024;
    const float* W; unsigned short* Wt; int K, N, nt, kt;
    if (b2 < 768)       { W = qkv_w; Wt = qkvw_t; K = 512;  N = 1536; nt = b2 % 48;          kt = b2 / 48; }
    else if (b2 < 1024) { W = out_w; Wt = outw_t; K = 512;  N = 512;  nt = (b2 - 768) % 16;  kt = (b2 - 768) / 16; }
    else if (b2 < 2048) { W = w1;    Wt = w1_t;   K = 512;  N = 2048; nt = (b2 - 1024) % 64; kt = (b2 - 1024) / 64; }
    else                { W = w2;    Wt = w2_t;   K = 2048; N = 512;  nt = (b2 - 2048) % 16; kt = (b2 - 2048) / 16; }
    const int tx = threadIdx.x & 31, ty = threadIdx.x >> 5;
    const int n0 = nt * 32, k0 = kt * 32;
    #pragma unroll
    for (int r = 0; r < 4; ++r)
        t[ty + r * 8][tx] = W[(size_t)(k0 + ty + r * 8) * N + n0 + tx];
    __syncthreads();
    #pragma unroll
    for (int r = 0; r < 4; ++r)
        Wt[(size_t)(n0 + ty + r * 8) * K + k0 + tx] = f2bf(t[tx][ty + r * 8]);
}

// ---------------------------------------------------------------------------
// Stage one BK=64 tile with 512 threads.
// LDS buf layout: Ah0 | Ah1 | Bh0 | Bh1, each [128 rows][64B].
// ---------------------------------------------------------------------------
__device__ __forceinline__ void stage64_8w(
    const unsigned short* __restrict__ A, const unsigned short* __restrict__ Bt,
    int K, int m0, int n0, int k0, char* buf, int tid)
{
    const int row = tid >> 2;
    const int kb  = (tid & 3) * 16;
    const char* pa = (const char*)A  + ((size_t)(m0 + row) * K + k0) * 2 + kb;
    const char* pb = (const char*)Bt + ((size_t)(n0 + row) * K + k0) * 2 + kb;
    char* dst = buf + tid * 16;
    gload16(pa,      dst);
    gload16(pa + 64, dst + 8192);
    gload16(pb,      dst + 16384);
    gload16(pb + 64, dst + 24576);
}

// ---------------------------------------------------------------------------
// GEMM core, 8 waves (512 thr), 128x128 tile, BK=64, 2-phase double buffer.
// ---------------------------------------------------------------------------
__device__ __forceinline__ void gemm_core_db8(
    const unsigned short* __restrict__ A, const unsigned short* __restrict__ Bt,
    int K, int m0, int n0, int kbeg, int kend, char* lds, f32x4 acc[4][2])
{
    const int tid  = threadIdx.x;
    const int lane = tid & 63;
    const int wave = tid >> 6;
    const int wr = wave >> 2, wc = wave & 3;
    const int lr = lane & 15, lk = lane >> 4;
    const int aoff = ((wr * 64 + lr) << 6) + (lk << 4);
    const int boff = 16384 + ((wc * 32 + lr) << 6) + (lk << 4);

    stage64_8w(A, Bt, K, m0, n0, kbeg, lds, tid);
    __syncthreads();

    int cur = 0;
    for (int k0 = kbeg; k0 < kend; k0 += 64) {
        char* bufc = lds + cur * 32768;
        if (k0 + 64 < kend)
            stage64_8w(A, Bt, K, m0, n0, k0 + 64, lds + (cur ^ 1) * 32768, tid);

        bf16x8 af[2][4], bfv[2][2];
        #pragma unroll
        for (int m = 0; m < 4; ++m) {
            af[0][m] = *(const bf16x8*)(bufc +        aoff + m * 1024);
            af[1][m] = *(const bf16x8*)(bufc + 8192 + aoff + m * 1024);
        }
        #pragma unroll
        for (int n = 0; n < 2; ++n) {
            bfv[0][n] = *(const bf16x8*)(bufc +        boff + n * 1024);
            bfv[1][n] = *(const bf16x8*)(bufc + 8192 + boff + n * 1024);
        }
        #pragma unroll
        for (int ks = 0; ks < 2; ++ks)
            #pragma unroll
            for (int m = 0; m < 4; ++m)
                #pragma unroll
                for (int n = 0; n < 2; ++n)
                    acc[m][n] = __builtin_amdgcn_mfma_f32_16x16x32_bf16(
                        af[ks][m], bfv[ks][n], acc[m][n], 0, 0, 0);

        __syncthreads();
        cur ^= 1;
    }
}

// ---------------------------------------------------------------------------
// Monolithic GEMM + bias (+ReLU), bf16 or fp32 out. 128x128 tile, 8 waves.
// ---------------------------------------------------------------------------
template <bool RELU, bool OUT_BF16>
__global__ __launch_bounds__(512) void gemm_mfma(
    const unsigned short* __restrict__ A,
    const unsigned short* __restrict__ Bt,
    const float* __restrict__ bias,
    void* __restrict__ Cv, int M, int N, int K)
{
    __shared__ __align__(16) char lds[65536];
    const int lane = threadIdx.x & 63;
    const int wave = threadIdx.x >> 6;
    const int wr = wave >> 2, wc = wave & 3;
    const int lr = lane & 15, lk = lane >> 4;

    const int wg = xcd_swizzle();
    const int bx = wg % gridDim.x, by = wg / gridDim.x;
    const int m0 = by * 128, n0 = bx * 128;

    f32x4 acc[4][2];
    #pragma unroll
    for (int m = 0; m < 4; ++m)
        #pragma unroll
        for (int n = 0; n < 2; ++n) acc[m][n] = f32x4{0.f, 0.f, 0.f, 0.f};

    gemm_core_db8(A, Bt, K, m0, n0, 0, K, lds, acc);

    const int col0 = n0 + wc * 32 + lr;
    const int row0 = m0 + wr * 64 + lk * 4;
    #pragma unroll
    for (int m = 0; m < 4; ++m)
        #pragma unroll
        for (int n = 0; n < 2; ++n) {
            int col = col0 + n * 16;
            float bv = bias[col];
            #pragma unroll
            for (int j = 0; j < 4; ++j) {
                int row = row0 + m * 16 + j;
                float v = acc[m][n][j] + bv;
                if (RELU) v = fmaxf(v, 0.0f);
                if (OUT_BF16)
                    ((unsigned short*)Cv)[(size_t)row * N + col] = f2bf(v);
                else
                    ((float*)Cv)[(size_t)row * N + col] = v;
            }
        }
}

// ---------------------------------------------------------------------------
// Split-K GEMM: chunk z covers [z*Kc,(z+1)*Kc); bf16 partial to P + z*M*N.
// ---------------------------------------------------------------------------
__global__ __launch_bounds__(512) void gemm_splitk(
    const unsigned short* __restrict__ A,
    const unsigned short* __restrict__ Bt,
    const float* __restrict__ bias,
    unsigned short* __restrict__ P, int M, int N, int K, int Kc)
{
    __shared__ __align__(16) char lds[65536];
    const int lane = threadIdx.x & 63;
    const int wave = threadIdx.x >> 6;
    const int wr = wave >> 2, wc = wave & 3;
    const int lr = lane & 15, lk = lane >> 4;

    const int wg = xcd_swizzle();
    const int bx = wg % gridDim.x;
    const int tmp = wg / gridDim.x;
    const int by = tmp % gridDim.y;
    const int zc = tmp / gridDim.y;
    const int m0 = by * 128, n0 = bx * 128;

    f32x4 acc[4][2];
    #pragma unroll
    for (int m = 0; m < 4; ++m)
        #pragma unroll
        for (int n = 0; n < 2; ++n) acc[m][n] = f32x4{0.f, 0.f, 0.f, 0.f};

    gemm_core_db8(A, Bt, K, m0, n0, zc * Kc, zc * Kc + Kc, lds, acc);

    unsigned short* Cp = P + (size_t)zc * M * N;
    const int col0 = n0 + wc * 32 + lr;
    const int row0 = m0 + wr * 64 + lk * 4;
    #pragma unroll
    for (int m = 0; m < 4; ++m)
        #pragma unroll
        for (int n = 0; n < 2; ++n) {
            int col = col0 + n * 16;
            float bv = (zc == 0) ? bias[col] : 0.0f;
            #pragma unroll
            for (int j = 0; j < 4; ++j) {
                int row = row0 + m * 16 + j;
                Cp[(size_t)row * N + col] = f2bf(acc[m][n][j] + bv);
            }
        }
}

// ---------------------------------------------------------------------------
// QKV GEMM: attention-layout epilogue. qb/kb [NH][SEQ][64], vtb [NH][64][SEQ].
// ---------------------------------------------------------------------------
__global__ __launch_bounds__(512) void gemm_qkv(
    const unsigned short* __restrict__ A,
    const unsigned short* __restrict__ Bt,
    const float* __restrict__ bias,
    unsigned short* __restrict__ qb,
    unsigned short* __restrict__ kb,
    unsigned short* __restrict__ vtb)
{
    constexpr int N = 3 * D, K = D;
    __shared__ __align__(16) char lds[65536];
    const int lane = threadIdx.x & 63;
    const int wave = threadIdx.x >> 6;
    const int wr = wave >> 2, wc = wave & 3;
    const int lr = lane & 15, lk = lane >> 4;

    const int wg = xcd_swizzle();
    const int bx = wg % gridDim.x, by = wg / gridDim.x;
    const int m0 = by * 128, n0 = bx * 128;

    f32x4 acc[4][2];
    #pragma unroll
    for (int m = 0; m < 4; ++m)
        #pragma unroll
        for (int n = 0; n < 2; ++n) acc[m][n] = f32x4{0.f, 0.f, 0.f, 0.f};

    gemm_core_db8(A, Bt, K, m0, n0, 0, K, lds, acc);

    const int col0 = n0 + wc * 32 + lr;
    const int row0 = m0 + wr * 64 + lk * 4;
    const int region = n0 >> 9;   // 0=Q, 1=K, 2=V (uniform per block)
    #pragma unroll
    for (int m = 0; m < 4; ++m)
        #pragma unroll
        for (int n = 0; n < 2; ++n) {
            const int col = col0 + n * 16;
            const float bv = bias[col];
            const int rowm = row0 + m * 16;
            if (region == 2) {
                const int cc = col - 1024, hh = cc >> 6, dd = cc & 63;
                ushort4 u = make_ushort4(f2bf(acc[m][n][0] + bv),
                                         f2bf(acc[m][n][1] + bv),
                                         f2bf(acc[m][n][2] + bv),
                                         f2bf(acc[m][n][3] + bv));
                *(ushort4*)&vtb[((size_t)(hh * 64 + dd)) * SEQ + rowm] = u;
            } else {
                const int cc = col - region * 512, hh = cc >> 6, dd = cc & 63;
                unsigned short* dst = (region == 0) ? qb : kb;
                #pragma unroll
                for (int j = 0; j < 4; ++j)
                    dst[((size_t)hh * SEQ + rowm + j) * 64 + dd] =
                        f2bf(acc[m][n][j] + bv);
            }
        }
}

// ---------------------------------------------------------------------------
// MFMA windowed attention with in-register chunk prefetch (T14 ping-pong).
// XCD-swizzled: head per XCD (nwg/8 = 64 = tiles/head).
// ---------------------------------------------------------------------------
__global__ __launch_bounds__(256) void attn_mfma(
    const unsigned short* __restrict__ qb,
    const unsigned short* __restrict__ kb,
    const unsigned short* __restrict__ vtb,
    unsigned short* __restrict__ o)
{
    constexpr float SCALE_L2E = 0.044194173824159216f * 1.4426950408889634f;
    __shared__ __align__(16) unsigned short P_lds[4][16][72];

    const int lane = threadIdx.x & 63;
    const int w    = threadIdx.x >> 6;

    const int wg = xcd_swizzle();          // nwg = 512
    const int i0 = (wg & 63) * 64;         // tile
    const int h  = wg >> 6;                // head
    const int lr = lane & 15, lg = lane >> 4;

    const unsigned short* qh = qb  + (size_t)h * SEQ * 64;
    const unsigned short* kh = kb  + (size_t)h * SEQ * 64;
    const unsigned short* vh = vtb + (size_t)h * 64 * SEQ;

    bf16x8 bq[2];
    {
        const unsigned short* qrow = qh + (size_t)(i0 + w * 16 + lr) * 64 + lg * 8;
        bq[0] = *(const bf16x8*)qrow;
        bq[1] = *(const bf16x8*)(qrow + 32);
    }

    f32x4 accO[4];
    #pragma unroll
    for (int n = 0; n < 4; ++n) accO[n] = f32x4{0.f, 0.f, 0.f, 0.f};
    float lsum = 0.0f;
    const int iq = i0 + w * 16 + lr;

    auto loadKV = [&](int c, bf16x8 (&ak)[2][4], bf16x8 (&bv)[2][4]) {
        const int j0 = i0 - WIN + c * 64;
        #pragma unroll
        for (int m = 0; m < 4; ++m) {
            const unsigned short* kr = kh + (size_t)(j0 + m * 16 + lr) * 64 + lg * 8;
            ak[0][m] = *(const bf16x8*)kr;
            ak[1][m] = *(const bf16x8*)(kr + 32);
        }
        #pragma unroll
        for (int n = 0; n < 4; ++n) {
            const unsigned short* vr = vh + (size_t)(n * 16 + lr) * SEQ + j0 + lg * 8;
            bv[0][n] = *(const bf16x8*)vr;
            bv[1][n] = *(const bf16x8*)(vr + 32);
        }
    };

    auto computeChunk = [&](int c, const bf16x8 (&ak)[2][4], const bf16x8 (&bv)[2][4]) {
        const int j0 = i0 - WIN + c * 64;
        f32x4 accS[4];
        #pragma unroll
        for (int m = 0; m < 4; ++m) {
            accS[m] = f32x4{0.f, 0.f, 0.f, 0.f};
            #pragma unroll
            for (int s = 0; s < 2; ++s)
                accS[m] = __builtin_amdgcn_mfma_f32_16x16x32_bf16(
                    ak[s][m], bq[s], accS[m], 0, 0, 0);
        }
        #pragma unroll
        for (int m = 0; m < 4; ++m) {
            const int kbase = j0 + m * 16 + lg * 4;
            int d0 = kbase + 0 - iq; bool v0 = (d0 >= -WIN) && (d0 <= WIN);
            int d1 = kbase + 1 - iq; bool v1 = (d1 >= -WIN) && (d1 <= WIN);
            int d2 = kbase + 2 - iq; bool v2 = (d2 >= -WIN) && (d2 <= WIN);
            int d3 = kbase + 3 - iq; bool v3 = (d3 >= -WIN) && (d3 <= WIN);
            float p0 = v0 ? exp2f(accS[m][0] * SCALE_L2E) : 0.0f;
            float p1 = v1 ? exp2f(accS[m][1] * SCALE_L2E) : 0.0f;
            float p2 = v2 ? exp2f(accS[m][2] * SCALE_L2E) : 0.0f;
            float p3 = v3 ? exp2f(accS[m][3] * SCALE_L2E) : 0.0f;
            lsum += (p0 + p1) + (p2 + p3);
            ushort4 pk = make_ushort4(f2bf(p0), f2bf(p1), f2bf(p2), f2bf(p3));
            *(ushort4*)&P_lds[w][lr][m * 16 + lg * 4] = pk;
        }
        bf16x8 pa[2];
        pa[0] = *(const bf16x8*)&P_lds[w][lr][lg * 8];
        pa[1] = *(const bf16x8*)&P_lds[w][lr][32 + lg * 8];
        #pragma unroll
        for (int n = 0; n < 4; ++n)
            #pragma unroll
            for (int s = 0; s < 2; ++s)
                accO[n] = __builtin_amdgcn_mfma_f32_16x16x32_bf16(
                    pa[s], bv[s][n], accO[n], 0, 0, 0);
    };

    // Valid chunk range: j0 = i0-128+c*64 in [0, SEQ-64]
    const int cmin = (i0 >= WIN) ? 0 : ((WIN - i0 + 63) >> 6);
    const int cmaxv = (SEQ + WIN - 64 - i0) >> 6;
    const int cmax = cmaxv < 4 ? cmaxv : 4;

    // Ping-pong register sets: prefetch c+1 while computing c.
    bf16x8 akA[2][4], bvA[2][4], akB[2][4], bvB[2][4];
    loadKV(cmin, akA, bvA);
    for (int c = cmin; c <= cmax; c += 2) {
        if (c + 1 <= cmax) loadKV(c + 1, akB, bvB);
        computeChunk(c, akA, bvA);
        if (c + 1 > cmax) break;
        if (c + 2 <= cmax) loadKV(c + 2, akA, bvA);
        computeChunk(c + 1, akB, bvB);
    }

    lsum += __shfl_xor(lsum, 16, 64);
    lsum += __shfl_xor(lsum, 32, 64);
    float rinv[4];
    #pragma unroll
    for (int j = 0; j < 4; ++j)
        rinv[j] = 1.0f / __shfl(lsum, lg * 4 + j, 64);

    #pragma unroll
    for (int n = 0; n < 4; ++n)
        #pragma unroll
        for (int j = 0; j < 4; ++j) {
            int row = i0 + w * 16 + lg * 4 + j;
            int col = h * 64 + n * 16 + lr;
            o[(size_t)row * D + col] = f2bf(accO[n][j] * rinv[j]);
        }
}

// ---------------------------------------------------------------------------
// out = LayerNorm(residual + sum_{p<NP} P_bf16[p]) * g + beta.
// Vectorized: lane owns 4 consecutive cols x 2 groups (c = lane*4 + e*256).
// ---------------------------------------------------------------------------
template <int NP, bool RES_BF16, bool OUT_BF16>
__global__ __launch_bounds__(256) void add_ln(
    const void* __restrict__ res, const unsigned short* __restrict__ P,
    size_t pstride,
    const float* __restrict__ g, const float* __restrict__ beta,
    void* __restrict__ out)
{
    const int wave = threadIdx.x >> 6;
    const int lane = threadIdx.x & 63;
    const int row = blockIdx.x * 4 + wave;
    const size_t rbase = (size_t)row * D;

    float v[2][4];
    float sum = 0.0f, sumsq = 0.0f;
    #pragma unroll
    for (int e = 0; e < 2; ++e) {
        const int c = lane * 4 + e * 256;
        float z0, z1, z2, z3;
        if (RES_BF16) {
            ushort4 u = *(const ushort4*)((const unsigned short*)res + rbase + c);
            z0 = bf2f(u.x); z1 = bf2f(u.y); z2 = bf2f(u.z); z3 = bf2f(u.w);
        } else {
            float4 f = *(const float4*)((const float*)res + rbase + c);
            z0 = f.x; z1 = f.y; z2 = f.z; z3 = f.w;
        }
        #pragma unroll
        for (int p = 0; p < NP; ++p) {
            ushort4 u = *(const ushort4*)(P + p * pstride + rbase + c);
            z0 += bf2f(u.x); z1 += bf2f(u.y); z2 += bf2f(u.z); z3 += bf2f(u.w);
        }
        v[e][0] = z0; v[e][1] = z1; v[e][2] = z2; v[e][3] = z3;
        sum   += (z0 + z1) + (z2 + z3);
        sumsq += (z0 * z0 + z1 * z1) + (z2 * z2 + z3 * z3);
    }
    #pragma unroll
    for (int off = 32; off; off >>= 1) {
        sum   += __shfl_xor(sum, off, 64);
        sumsq += __shfl_xor(sumsq, off, 64);
    }
    const float mu   = sum * (1.0f / D);
    const float var  = sumsq * (1.0f / D) - mu * mu;
    const float rstd = rsqrtf(var + LN_EPS);

    #pragma unroll
    for (int e = 0; e < 2; ++e) {
        const int c = lane * 4 + e * 256;
        float4 gv = *(const float4*)(g + c);
        float4 bb = *(const float4*)(beta + c);
        float r0 = (v[e][0] - mu) * rstd * gv.x + bb.x;
        float r1 = (v[e][1] - mu) * rstd * gv.y + bb.y;
        float r2 = (v[e][2] - mu) * rstd * gv.z + bb.z;
        float r3 = (v[e][3] - mu) * rstd * gv.w + bb.w;
        if (OUT_BF16) {
            ushort4 u = make_ushort4(f2bf(r0), f2bf(r1), f2bf(r2), f2bf(r3));
            *(ushort4*)((unsigned short*)out + rbase + c) = u;
        } else {
            *(float4*)((float*)out + rbase + c) = make_float4(r0, r1, r2, r3);
        }
    }
}

// ---------------------------------------------------------------------------
extern "C" void kernel_launch(void* const* d_in, const int* in_sizes, int n_in,
                              void* d_out, int out_size, void* d_ws, size_t ws_size,
                              hipStream_t stream)
{
    const float* x      = (const float*)d_in[0];
    const float* qkv_w  = (const float*)d_in[1];
    const float* qkv_b  = (const float*)d_in[2];
    const float* out_w  = (const float*)d_in[3];
    const float* out_b  = (const float*)d_in[4];
    const float* ln1_g  = (const float*)d_in[5];
    const float* ln1_b  = (const float*)d_in[6];
    const float* w1     = (const float*)d_in[7];
    const float* b1     = (const float*)d_in[8];
    const float* w2     = (const float*)d_in[9];
    const float* b2     = (const float*)d_in[10];
    const float* ln2_g  = (const float*)d_in[11];
    const float* ln2_b  = (const float*)d_in[12];
    float* out = (float*)d_out;

    // ---- workspace layout (flat, no aliasing; 70 MiB total) ----
    constexpr size_t MiB = 1u << 20;
    char* base = (char*)d_ws;
    unsigned short* xb     = (unsigned short*)(base + 0);                     // 4
    unsigned short* qkvw_t = (unsigned short*)(base + 4 * MiB);               // 1.5
    unsigned short* outw_t = (unsigned short*)(base + 5 * MiB + 512 * 1024);  // 0.5
    unsigned short* w1_t   = (unsigned short*)(base + 6 * MiB);               // 2
    unsigned short* w2_t   = (unsigned short*)(base + 8 * MiB);               // 2
    unsigned short* qbuf   = (unsigned short*)(base + 10 * MiB);              // 4
    unsigned short* kbuf   = (unsigned short*)(base + 14 * MiB);              // 4
    unsigned short* vtbuf  = (unsigned short*)(base + 18 * MiB);              // 4
    unsigned short* o_b    = (unsigned short*)(base + 22 * MiB);              // 4
    unsigned short* pOut   = (unsigned short*)(base + 26 * MiB);              // 8  (2 partials)
    unsigned short* x1b    = (unsigned short*)(base + 34 * MiB);              // 4
    unsigned short* ff1b   = (unsigned short*)(base + 38 * MiB);              // 16
    unsigned short* pFF2   = (unsigned short*)(base + 54 * MiB);              // 16 (4 partials)

    // 0) conversions + weight transposes (one kernel)
    prep<<<4096, 256, 0, stream>>>(x, xb, qkv_w, out_w, w1, w2,
                                   qkvw_t, outw_t, w1_t, w2_t);

    // 1) qkv projection -> qb/kb/vtb (8-wave 2-phase dbuf, XCD-swizzled)
    gemm_qkv<<<dim3(3 * D / 128, SEQ / 128), 512, 0, stream>>>(
        xb, qkvw_t, qkv_b, qbuf, kbuf, vtbuf);

    // 2) MFMA windowed attention -> o bf16 (chunk-prefetch, head per XCD)
    attn_mfma<<<dim3(SEQ / 64, NH), 256, 0, stream>>>(qbuf, kbuf, vtbuf, o_b);

    // 3) out-proj, split-K 2 -> bf16 partials
    gemm_splitk<<<dim3(D / 128, SEQ / 128, 2), 512, 0, stream>>>(
        o_b, outw_t, out_b, pOut, SEQ, D, D, D / 2);

    // 4) x1b = bf16( LN(x + p0 + p1) )
    add_ln<2, false, true><<<SEQ / 4, 256, 0, stream>>>(
        x, pOut, (size_t)SEQ * D, ln1_g, ln1_b, x1b);

    // 5) ff1 = relu(x1b @ w1 + b1) -> bf16
    gemm_mfma<true, true><<<dim3(DFF / 128, SEQ / 128), 512, 0, stream>>>(
        x1b, w1_t, b1, ff1b, SEQ, DFF, D);

    // 6) ff2 split-K 4 -> bf16 partials
    gemm_splitk<<<dim3(D / 128, SEQ / 128, 4), 512, 0, stream>>>(
        ff1b, w2_t, b2, pFF2, SEQ, D, DFF, DFF / 4);

    // 7) out = LN(x1b + p0+p1+p2+p3) -> fp32
    add_ln<4, true, false><<<SEQ / 4, 256, 0, stream>>>(
        x1b, pFF2, (size_t)SEQ * D, ln2_g, ln2_b, out);
}